// Round 13
// baseline (460.294 us; speedup 1.0000x reference)
//
#include <hip/hip_runtime.h>
#include <hip/hip_bf16.h>

// Problem constants (static per reference)
#define NN   512    // nodes
#define EE   512    // edges == nb-graph nodes (En)
#define MM   16384  // nb-graph edges

typedef float v4f __attribute__((ext_vector_type(4)));
typedef short short8v __attribute__((ext_vector_type(8)));

__device__ __forceinline__ float silu_f(float v) { return v / (1.0f + __expf(-v)); }

// ---------------- K1: per original edge: coord_diff + efn = MLP([h_r|h_c]) ----
__global__ __launch_bounds__(128) void k_edge(
    const float* __restrict__ h, const float* __restrict__ x,
    const int* __restrict__ edges,
    const float* __restrict__ ew1, const float* __restrict__ eb1,
    const float* __restrict__ ew2, const float* __restrict__ eb2,
    float* __restrict__ coord_diff, float* __restrict__ efn) {
  __shared__ float hin[128];
  __shared__ float hs[128];
  int e = blockIdx.x;
  int t = threadIdx.x;
  int r = edges[e], c = edges[EE + e];
  if (t < 3) coord_diff[e * 3 + t] = x[r * 3 + t] - x[c * 3 + t];
  if (t < 64) { hin[t] = h[r * 64 + t]; hin[64 + t] = h[c * 64 + t]; }
  __syncthreads();
  float acc = eb1[t];
  for (int k = 0; k < 128; ++k) acc += hin[k] * ew1[k * 128 + t];
  hs[t] = silu_f(acc);
  __syncthreads();
  if (t < 64) {
    float o = eb2[t];
    for (int k = 0; k < 128; ++k) o += hs[k] * ew2[k * 64 + t];
    efn[e * 64 + t] = o;
  }
}

// ---------------- K2: constants c1 = MLP1(0), c2 = MLP2(0) -------------------
__global__ __launch_bounds__(128) void k_consts(
    const float* __restrict__ p1b1, const float* __restrict__ p1w2, const float* __restrict__ p1b2,
    const float* __restrict__ p2b1, const float* __restrict__ p2w2, const float* __restrict__ p2b2,
    float* __restrict__ c1, float* __restrict__ c2) {
  __shared__ float h1[128], h2[128];
  int t = threadIdx.x;
  h1[t] = silu_f(p1b1[t]); h2[t] = silu_f(p2b1[t]);
  __syncthreads();
  if (t < 64) {
    float a1 = p1b2[t], a2 = p2b2[t];
    for (int k = 0; k < 128; ++k) { a1 += h1[k] * p1w2[k * 64 + t]; a2 += h2[k] * p2w2[k * 64 + t]; }
    c1[t] = a1; c2[t] = a2;
  }
}

// ---------------- K2b: Wt[h][f] = bf16(p3w1[96+f][h]) (B-operand for MFMA) ---
__global__ __launch_bounds__(256) void k_prep(const float* __restrict__ p3w1,
                                              __hip_bfloat16* __restrict__ Wt) {
  int e = blockIdx.x * 256 + threadIdx.x;   // 8192 = 128 h x 64 f
  int hh = e >> 6, f = e & 63;
  Wt[hh * 64 + f] = __float2bfloat16(p3w1[(96 + f) * 128 + hh]);
}

// ---------------- K2c: bf16 copies of the five mlp96 weight matrices ---------
__global__ __launch_bounds__(256) void k_prepw(
    const float* __restrict__ w11, const float* __restrict__ w21,
    const float* __restrict__ p3w1,
    const float* __restrict__ w12, const float* __restrict__ w22,
    __hip_bfloat16* __restrict__ w11b, __hip_bfloat16* __restrict__ w21b,
    __hip_bfloat16* __restrict__ pw1b,
    __hip_bfloat16* __restrict__ w12b, __hip_bfloat16* __restrict__ w22b) {
  int e = blockIdx.x * 256 + threadIdx.x;   // 53248 total
  if (e < 12288) w11b[e] = __float2bfloat16(w11[e]);
  else if (e < 24576) w21b[e - 12288] = __float2bfloat16(w21[e - 12288]);
  else if (e < 36864) pw1b[e - 24576] = __float2bfloat16(p3w1[e - 24576]);
  else if (e < 45056) w12b[e - 36864] = __float2bfloat16(w12[e - 36864]);
  else if (e < 53248) w22b[e - 45056] = __float2bfloat16(w22[e - 45056]);
}

// ---------------- K3: mark touched cells -------------------------------------
__global__ __launch_bounds__(256) void k_mark(const int* __restrict__ nb_edge,
                                              int* __restrict__ slotmap) {
  int m = blockIdx.x * 256 + threadIdx.x;
  if (m >= MM) return;
  int cell = nb_edge[m] * 512 + nb_edge[MM + m];
  atomicCAS(&slotmap[cell], -1, -2);
}

// ------ K4: compact marked cells -> slots (both orientations) ----------------
__global__ __launch_bounds__(256) void k_compact(int* __restrict__ slotmap,
                                                 int* __restrict__ slotmapT,
                                                 int* __restrict__ cells,
                                                 int* __restrict__ nC) {
  int cell = blockIdx.x * 256 + threadIdx.x;
  if (slotmap[cell] != -2) return;
  int s = atomicAdd(nC, 1);
  slotmap[cell] = s;
  slotmapT[(cell & 511) * 512 + (cell >> 9)] = s;
  cells[s] = cell;
}

// ---------------- K7: nb_feat scatter-add into COMPACT Tc (2 edges/block) ----
__global__ __launch_bounds__(192) void k_scatterT(
    const int* __restrict__ nb_edge, const int* __restrict__ slotmap,
    const float* __restrict__ coord_diff, const float* __restrict__ efn,
    float* __restrict__ Tc) {
  int t = threadIdx.x;
  int sub = (t >= 96) ? 1 : 0;
  int c = t - sub * 96;
  int m = blockIdx.x * 2 + sub;
  int a = nb_edge[m], b = nb_edge[MM + m];
  int s = slotmap[a * 512 + b];
  float val;
  if (c < 32) {
    float vtv = coord_diff[a * 3 + 0] * coord_diff[b * 3 + 0]
              + coord_diff[a * 3 + 1] * coord_diff[b * 3 + 1]
              + coord_diff[a * 3 + 2] * coord_diff[b * 3 + 2];
    int i = c >> 1;
    float ang = vtv * 16.0f * __expf(-0.57564627324851143f * (float)i);
    val = (c & 1) ? cosf(ang) : sinf(ang);
  } else {
    int f = c - 32;
    val = efn[a * 64 + f] * efn[b * 64 + f];
  }
  atomicAdd(&Tc[s * 96 + c], val);
}

// ------- K8: batched (16 cells/block) MLPs, bf16 weights ---------------------
// -> D1/D2, sums A,B; TWc = Tc @ w1T. Padding cells are zero rows of Tc.
__global__ __launch_bounds__(128) void k_mlp96b(
    const int* __restrict__ cells, const int* __restrict__ nC, const float* __restrict__ Tc,
    const __hip_bfloat16* __restrict__ w11b, const float* __restrict__ b11,
    const __hip_bfloat16* __restrict__ w12b, const float* __restrict__ b12,
    const __hip_bfloat16* __restrict__ w21b, const float* __restrict__ b21,
    const __hip_bfloat16* __restrict__ w22b, const float* __restrict__ b22,
    const float* __restrict__ c1, const float* __restrict__ c2,
    const __hip_bfloat16* __restrict__ pw1b,
    float* __restrict__ D1, float* __restrict__ D2,
    float* __restrict__ A, float* __restrict__ B,
    float* __restrict__ TWc) {
  __shared__ float xsT[96 * 16];   // [k][cell] 6 KB
  __shared__ float hid[16][128];   // 8 KB
  __shared__ int cl[16];
  int t = threadIdx.x;
  int nc = *nC;
  int s0 = blockIdx.x * 16;
  if (s0 >= nc) return;
  for (int e = t; e < 1536; e += 128) xsT[(e % 96) * 16 + e / 96] = Tc[s0 * 96 + e];
  if (t < 16) cl[t] = (s0 + t < nc) ? cells[s0 + t] : 0;
  __syncthreads();
  float tw[16], a1[16], a2[16];
#pragma unroll
  for (int c = 0; c < 16; ++c) { tw[c] = 0.f; a1[c] = b11[t]; a2[c] = b21[t]; }
  for (int k = 0; k < 96; ++k) {
    float wt = __bfloat162float(pw1b[k * 128 + t]);
    float w1v = __bfloat162float(w11b[k * 128 + t]);
    float w2v = __bfloat162float(w21b[k * 128 + t]);
    float4 x0 = *(const float4*)&xsT[k * 16];
    float4 x1 = *(const float4*)&xsT[k * 16 + 4];
    float4 x2 = *(const float4*)&xsT[k * 16 + 8];
    float4 x3 = *(const float4*)&xsT[k * 16 + 12];
    float xv[16] = {x0.x, x0.y, x0.z, x0.w, x1.x, x1.y, x1.z, x1.w,
                    x2.x, x2.y, x2.z, x2.w, x3.x, x3.y, x3.z, x3.w};
#pragma unroll
    for (int c = 0; c < 16; ++c) {
      tw[c] += xv[c] * wt; a1[c] += xv[c] * w1v; a2[c] += xv[c] * w2v;
    }
  }
#pragma unroll
  for (int c = 0; c < 16; ++c) {
    if (s0 + c < nc) TWc[(s0 + c) * 128 + t] = tw[c];
    hid[c][t] = silu_f(a1[c]);
  }
  __syncthreads();
  {
    int hh = t & 63, cq = t >> 6;   // 2 groups x 8 cells
    float o[8];
#pragma unroll
    for (int cc = 0; cc < 8; ++cc) o[cc] = b12[hh];
    for (int k = 0; k < 128; ++k) {
      float w = __bfloat162float(w12b[k * 64 + hh]);
#pragma unroll
      for (int cc = 0; cc < 8; ++cc) o[cc] += hid[cq * 8 + cc][k] * w;
    }
#pragma unroll
    for (int cc = 0; cc < 8; ++cc) {
      int c = cq * 8 + cc;
      if (s0 + c < nc) {
        float d = o[cc] - c1[hh];
        D1[(s0 + c) * 64 + hh] = d;
        atomicAdd(&A[(cl[c] >> 9) * 64 + hh], d);
      }
    }
  }
  __syncthreads();
#pragma unroll
  for (int c = 0; c < 16; ++c) hid[c][t] = silu_f(a2[c]);
  __syncthreads();
  {
    int hh = t & 63, cq = t >> 6;
    float o[8];
#pragma unroll
    for (int cc = 0; cc < 8; ++cc) o[cc] = b22[hh];
    for (int k = 0; k < 128; ++k) {
      float w = __bfloat162float(w22b[k * 64 + hh]);
#pragma unroll
      for (int cc = 0; cc < 8; ++cc) o[cc] += hid[cq * 8 + cc][k] * w;
    }
#pragma unroll
    for (int cc = 0; cc < 8; ++cc) {
      int c = cq * 8 + cc;
      if (s0 + c < nc) {
        float d = o[cc] - c2[hh];
        D2[(s0 + c) * 64 + hh] = d;
        atomicAdd(&B[(cl[c] & 511) * 64 + hh], d);
      }
    }
  }
}

// ---------------- K10: u[i] = b1 + (512 c1c2 + c2*A[i])@w1m ; v[j] = (c1*B[j])@w1m
__global__ __launch_bounds__(128) void k_uv(
    const float* __restrict__ A, const float* __restrict__ B,
    const float* __restrict__ c1, const float* __restrict__ c2,
    const float* __restrict__ p3w1, const float* __restrict__ p3b1,
    float* __restrict__ u, float* __restrict__ v) {
  __shared__ float vec[64];
  int i = blockIdx.x, y = blockIdx.y, t = threadIdx.x;
  if (t < 64)
    vec[t] = (y == 0) ? (512.0f * c1[t] * c2[t] + c2[t] * A[i * 64 + t])
                      : (c1[t] * B[i * 64 + t]);
  __syncthreads();
  float a = (y == 0) ? p3b1[t] : 0.f;
  for (int f = 0; f < 64; ++f) a += vec[f] * p3w1[(96 + f) * 128 + t];
  (y == 0 ? u : v)[i * 128 + t] = a;
}

// ---------------- K11a: densify compact D1/D2 into plane-major bf16 ----------
__global__ __launch_bounds__(512) void k_densify(
    const int* __restrict__ slotmap, const int* __restrict__ slotmapT,
    const float* __restrict__ D1, const float* __restrict__ D2,
    __hip_bfloat16* __restrict__ D1d, __hip_bfloat16* __restrict__ D2dT) {
  int k = threadIdx.x;
  int i = blockIdx.x;
  int y = blockIdx.y;
  if (y < 64) {
    int f = y;
    int s = slotmap[i * 512 + k];
    float v = (s >= 0) ? D1[s * 64 + f] : 0.f;
    D1d[(f * 512 + i) * 512 + k] = __float2bfloat16(v);
  } else {
    int f = y - 64;
    int s = slotmapT[i * 512 + k];
    float v = (s >= 0) ? D2[s * 64 + f] : 0.f;
    D2dT[(f * 512 + i) * 512 + k] = __float2bfloat16(v);
  }
}

// ---------------- K11b: batched plane GEMM S_f = A_f * B_f (MFMA) ------------
__global__ __launch_bounds__(256) void k_einsum_mfma(
    const __hip_bfloat16* __restrict__ D1d,
    const __hip_bfloat16* __restrict__ D2dT,
    __hip_bfloat16* __restrict__ S_fij) {
  __shared__ short As[128 * 40];
  __shared__ short Bs[128 * 40];
  int b = blockIdx.x;
  int f = b >> 4;
  int i0 = ((b >> 2) & 3) * 128, j0 = (b & 3) * 128;
  int t = threadIdx.x;
  int w = t >> 6, lane = t & 63;
  int wy = w >> 1, wx = w & 1;
  int q = lane >> 4, l15 = lane & 15;
  const short* Ap = (const short*)D1d + f * 262144;
  const short* Bp = (const short*)D2dT + f * 262144;
  int row = t >> 1, seg = t & 1;   // staging: 128 rows x 2 segments of 16
  v4f acc[4][4];
#pragma unroll
  for (int yi = 0; yi < 4; ++yi)
#pragma unroll
    for (int xj = 0; xj < 4; ++xj) acc[yi][xj] = (v4f){0.f, 0.f, 0.f, 0.f};
  for (int k0 = 0; k0 < 512; k0 += 32) {
    __syncthreads();
    const short8v* ga = (const short8v*)&Ap[(i0 + row) * 512 + k0 + seg * 16];
    const short8v* gb = (const short8v*)&Bp[(j0 + row) * 512 + k0 + seg * 16];
    *(short8v*)&As[row * 40 + seg * 16] = ga[0];
    *(short8v*)&As[row * 40 + seg * 16 + 8] = ga[1];
    *(short8v*)&Bs[row * 40 + seg * 16] = gb[0];
    *(short8v*)&Bs[row * 40 + seg * 16 + 8] = gb[1];
    __syncthreads();
    short8v af[4], bf[4];
#pragma unroll
    for (int x = 0; x < 4; ++x) {
      af[x] = *(const short8v*)&As[(wy * 64 + x * 16 + l15) * 40 + q * 8];
      bf[x] = *(const short8v*)&Bs[(wx * 64 + x * 16 + l15) * 40 + q * 8];
    }
#pragma unroll
    for (int yi = 0; yi < 4; ++yi)
#pragma unroll
      for (int xj = 0; xj < 4; ++xj)
        acc[yi][xj] = __builtin_amdgcn_mfma_f32_16x16x32_bf16(af[yi], bf[xj], acc[yi][xj], 0, 0, 0);
  }
  // C layout: col j = l15, row i = q*4 + r  [m89-verified]
#pragma unroll
  for (int yi = 0; yi < 4; ++yi)
#pragma unroll
    for (int r = 0; r < 4; ++r) {
      int irow = i0 + wy * 64 + yi * 16 + q * 4 + r;
#pragma unroll
      for (int xj = 0; xj < 4; ++xj)
        S_fij[(f * 512 + irow) * 512 + j0 + wx * 64 + xj * 16 + l15] =
            __float2bfloat16(acc[yi][xj][r]);
    }
}

// ---------------- K11c: transpose S_fij [64][262144] -> S [262144][64] -------
__global__ __launch_bounds__(256) void k_transpose(
    const __hip_bfloat16* __restrict__ S_fij, __hip_bfloat16* __restrict__ S) {
  __shared__ short lds[64 * 72];
  int t = threadIdx.x;
  int ij0 = blockIdx.x * 64;
  const short* src = (const short*)S_fij;
#pragma unroll
  for (int p = 0; p < 2; ++p) {
    int f = p * 32 + (t >> 3), seg = t & 7;
    short8v ga = *(const short8v*)&src[f * 262144 + ij0 + seg * 8];
    int fgrp = f >> 3, flo = f & 7;
#pragma unroll
    for (int k = 0; k < 8; ++k) {
      int ij = seg * 8 + k;
      int swz = (fgrp ^ (ij & 7) ^ ((ij >> 3) & 7)) & 7;
      lds[ij * 72 + swz * 8 + flo] = ga[k];
    }
  }
  __syncthreads();
  short* dst = (short*)S;
#pragma unroll
  for (int p = 0; p < 2; ++p) {
    int ij = p * 32 + (t >> 3), fseg = t & 7;
    int swz = (fseg ^ (ij & 7) ^ ((ij >> 3) & 7)) & 7;
    short8v val = *(const short8v*)&lds[ij * 72 + swz * 8];
    *(short8v*)&dst[(ij0 + ij) * 64 + fseg * 8] = val;
  }
}

// ------- K12: MFMA z = S@Wt + u[i]+v[j]+TW, silu, row/col/diag reduce --------
// v3.1: 16x16-cell tile (grid 1024); bf16 uvL/colbuf -> 45.5 KB LDS, 3 blk/CU.
// C layout [m89]: n(h) = l15, m = q*4+r -> jL = q*4+r, iL fixed per M-tile.
__global__ __launch_bounds__(256) void k_tout_mfma(
    const __hip_bfloat16* __restrict__ S, const float* __restrict__ u,
    const float* __restrict__ v, const float* __restrict__ TWc,
    const int* __restrict__ slotmap, const __hip_bfloat16* __restrict__ Wt,
    float* __restrict__ row_part, float* __restrict__ col_part,
    float* __restrict__ diag_silu) {
  __shared__ __hip_bfloat16 WtL[128 * 72];         // 18,432 B
  __shared__ __hip_bfloat16 uvL[4096];             // 8,192 B (u 16x128 | v 16x128)
  __shared__ __hip_bfloat16 colbuf[4][16][140];    // 17,920 B (pad 140 -> banks spread)
  __shared__ int slotL[256];
  int t = threadIdx.x;
  int w = t >> 6, lane = t & 63;
  int q = lane >> 4, l15 = lane & 15;
  int bi = blockIdx.x >> 5, bj = blockIdx.x & 31;
  int i0 = bi * 16, j0 = bj * 16;
  for (int e = t; e < 4096; e += 256) {
    int row = e >> 5, c2 = e & 31;
    ((unsigned*)WtL)[row * 36 + c2] = ((const unsigned*)Wt)[row * 32 + c2];
  }
  for (int e = t; e < 2048; e += 256)
    uvL[e] = __float2bfloat16(u[(i0 + (e >> 7)) * 128 + (e & 127)]);
  for (int e = t; e < 2048; e += 256)
    uvL[2048 + e] = __float2bfloat16(v[(j0 + (e >> 7)) * 128 + (e & 127)]);
  slotL[t] = slotmap[(i0 + (t >> 4)) * 512 + j0 + (t & 15)];
  // A-frags: M-tile mt = row i0+w*4+mt, cols j0..j0+15 (lane l15 = jL)
  short8v a[4][2];
#pragma unroll
  for (int mt = 0; mt < 4; ++mt) {
    const short8v* sp =
        (const short8v*)&S[((i0 + w * 4 + mt) * 512 + j0 + l15) * 64];
    a[mt][0] = sp[q];
    a[mt][1] = sp[4 + q];
  }
  __syncthreads();
#pragma unroll
  for (int half = 0; half < 2; ++half) {
    v4f acc[4][4];
#pragma unroll
    for (int mt = 0; mt < 4; ++mt)
#pragma unroll
      for (int n4 = 0; n4 < 4; ++n4) {
        int nt = half * 4 + n4;
        const short8v* b0 = (const short8v*)&WtL[(nt * 16 + l15) * 72 + q * 8];
        const short8v* b1 = (const short8v*)&WtL[(nt * 16 + l15) * 72 + 32 + q * 8];
        v4f c = {0.f, 0.f, 0.f, 0.f};
        c = __builtin_amdgcn_mfma_f32_16x16x32_bf16(a[mt][0], *b0, c, 0, 0, 0);
        c = __builtin_amdgcn_mfma_f32_16x16x32_bf16(a[mt][1], *b1, c, 0, 0, 0);
        acc[mt][n4] = c;
      }
#pragma unroll
    for (int n4 = 0; n4 < 4; ++n4) {
      int nt = half * 4 + n4;
      int hh = nt * 16 + l15;
      float rs[4] = {0.f, 0.f, 0.f, 0.f};
#pragma unroll
      for (int r = 0; r < 4; ++r) {
        int jL = q * 4 + r;
        float cs = 0.f;
        float vv = __bfloat162float(uvL[2048 + jL * 128 + hh]);
#pragma unroll
        for (int mt = 0; mt < 4; ++mt) {
          int iL = w * 4 + mt;
          float z = acc[mt][n4][r] + __bfloat162float(uvL[iL * 128 + hh]) + vv;
          int s = slotL[iL * 16 + jL];
          if (s >= 0) z += TWc[s * 128 + hh];
          float sv = silu_f(z);
          rs[mt] += sv;
          cs += sv;
          if (bi == bj && iL == jL) diag_silu[(i0 + iL) * 128 + hh] = sv;
        }
        colbuf[w][jL][hh] = __float2bfloat16(cs);  // unique (jL,hh) per lane
      }
#pragma unroll
      for (int mt = 0; mt < 4; ++mt) {
        float rsum = rs[mt];
        rsum += __shfl_xor(rsum, 16);
        rsum += __shfl_xor(rsum, 32);
        if (q == 0)
          row_part[(bj * 512 + i0 + w * 4 + mt) * 128 + hh] = rsum;
      }
    }
  }
  __syncthreads();
  for (int e = t; e < 2048; e += 256) {
    int jL = e >> 7, hh = e & 127;
    float acc4 = __bfloat162float(colbuf[0][jL][hh]) + __bfloat162float(colbuf[1][jL][hh]) +
                 __bfloat162float(colbuf[2][jL][hh]) + __bfloat162float(colbuf[3][jL][hh]);
    col_part[(bi * 512 + j0 + jL) * 128 + hh] = acc4;
  }
}

// ---------------- K13: reduce 32 partial slices ------------------------------
__global__ __launch_bounds__(256) void k_sumparts(
    const float* __restrict__ row_part, const float* __restrict__ col_part,
    float* __restrict__ rowsum, float* __restrict__ colsum) {
  int i = blockIdx.x, t = threadIdx.x;
  const float* src = (t < 128) ? row_part : col_part;
  float* dst = (t < 128) ? rowsum : colsum;
  int hc = t & 127;
  float a = 0.f;
  for (int p = 0; p < 32; ++p) a += src[(p * 512 + i) * 128 + hc];
  dst[i * 128 + hc] = a;
}

// ---------------- K14: second layer of p3 MLP on reduced silu sums -----------
__global__ __launch_bounds__(64) void k_tout2(
    const float* __restrict__ diag_silu, const float* __restrict__ rowsum_silu,
    const float* __restrict__ colsum_silu,
    const float* __restrict__ w2, const float* __restrict__ b2,
    float* __restrict__ diag_T, float* __restrict__ row_T, float* __restrict__ col_T) {
  __shared__ float in[128];
  int e = blockIdx.x, which = blockIdx.y, t = threadIdx.x;
  const float* src = (which == 0) ? diag_silu : (which == 1) ? rowsum_silu : colsum_silu;
  in[t] = src[e * 128 + t]; in[64 + t] = src[e * 128 + 64 + t];
  __syncthreads();
  float a = 0.f;
  for (int k = 0; k < 128; ++k) a += in[k] * w2[k * 64 + t];
  float bias = b2[t] * ((which == 0) ? 1.0f : 512.0f);
  float* dst = (which == 0) ? diag_T : (which == 1) ? row_T : col_T;
  dst[e * 64 + t] = a + bias;
}

// ---------------- K15: tot / tr ----------------------------------------------
__global__ __launch_bounds__(128) void k_totr(
    const float* __restrict__ row_T, const float* __restrict__ diag_T,
    float* __restrict__ tot, float* __restrict__ tr) {
  int t = threadIdx.x;
  const float* src = (t < 64) ? row_T : diag_T;
  int f = t & 63;
  float a = 0.f;
  for (int e = 0; e < 512; ++e) a += src[e * 64 + f];
  if (t < 64) tot[f] = a; else tr[f] = a;
}

// ---------------- K16: nb_t1 = [diag|row|col|tot|tr] @ ign_w + ign_b ---------
__global__ __launch_bounds__(64) void k_nbt1(
    const float* __restrict__ diag_T, const float* __restrict__ row_T,
    const float* __restrict__ col_T, const float* __restrict__ tot,
    const float* __restrict__ tr,
    const float* __restrict__ gw, const float* __restrict__ gb,
    float* __restrict__ nb_t1) {
  __shared__ float in[320];
  int e = blockIdx.x, t = threadIdx.x;
  in[t] = diag_T[e * 64 + t]; in[64 + t] = row_T[e * 64 + t];
  in[128 + t] = col_T[e * 64 + t]; in[192 + t] = tot[t]; in[256 + t] = tr[t];
  __syncthreads();
  float a = gb[t];
  for (int k = 0; k < 320; ++k) a += in[k] * gw[k * 64 + t];
  nb_t1[e * 64 + t] = a;
}

// ----- K17: coord weight w_e, seg/cnt/nb_t0 scatters, edge_attr passthrough --
__global__ __launch_bounds__(128) void k_edge_out(
    const int* __restrict__ edges, const float* __restrict__ coord_diff,
    const float* __restrict__ nb_t1, const float* __restrict__ edge_attr,
    const float* __restrict__ cw1, const float* __restrict__ cb1,
    const float* __restrict__ cw2,
    float* __restrict__ seg, float* __restrict__ cnt, float* __restrict__ nb_t0,
    float* __restrict__ out_ea) {
  __shared__ float in[64];
  __shared__ float red[128];
  int e = blockIdx.x, t = threadIdx.x;
  if (t < 64) in[t] = nb_t1[e * 64 + t];
  __syncthreads();
  float a = cb1[t];
  for (int k = 0; k < 64; ++k) a += in[k] * cw1[k * 128 + t];
  red[t] = silu_f(a) * cw2[t];
  __syncthreads();
  for (int s2 = 64; s2 > 0; s2 >>= 1) {
    if (t < s2) red[t] += red[t + s2];
    __syncthreads();
  }
  float w = red[0];
  int r = edges[e];
  if (t < 3) atomicAdd(&seg[r * 3 + t], coord_diff[e * 3 + t] * w);
  if (t == 64) atomicAdd(&cnt[r], 1.0f);
  if (t < 64) atomicAdd(&nb_t0[r * 64 + t], in[t]);
  if (t < 4) out_ea[e * 4 + t] = edge_attr[e * 4 + t];
}

// ---------------- K18: x_new and h_new ---------------------------------------
__global__ __launch_bounds__(128) void k_node_out(
    const float* __restrict__ h, const float* __restrict__ x,
    const float* __restrict__ seg, const float* __restrict__ cnt,
    const float* __restrict__ nb_t0,
    const float* __restrict__ w1, const float* __restrict__ b1,
    const float* __restrict__ w2, const float* __restrict__ b2,
    float* __restrict__ out_h, float* __restrict__ out_x) {
  __shared__ float in[64];
  __shared__ float hs[128];
  int n = blockIdx.x, t = threadIdx.x;
  if (t < 3) {
    float c = cnt[n]; if (c < 1.f) c = 1.f;
    out_x[n * 3 + t] = x[n * 3 + t] + seg[n * 3 + t] / c;
  }
  if (t < 64) in[t] = nb_t0[n * 64 + t];
  __syncthreads();
  float a = b1[t];
  for (int k = 0; k < 64; ++k) a += in[k] * w1[k * 128 + t];
  hs[t] = silu_f(a);
  __syncthreads();
  if (t < 64) {
    float o = b2[t];
    for (int k = 0; k < 128; ++k) o += hs[k] * w2[k * 64 + t];
    out_h[n * 64 + t] = h[n * 64 + t] + o;
  }
}

extern "C" void kernel_launch(void* const* d_in, const int* in_sizes, int n_in,
                              void* d_out, int out_size, void* d_ws, size_t ws_size,
                              hipStream_t stream) {
  (void)in_sizes; (void)n_in; (void)out_size; (void)ws_size;
  const float* h  = (const float*)d_in[0];
  const float* x  = (const float*)d_in[1];
  const int* edges   = (const int*)d_in[2];
  const int* nb_edge = (const int*)d_in[3];
  const float* edge_attr = (const float*)d_in[4];
  const float* ew1 = (const float*)d_in[6],  *eb1 = (const float*)d_in[7];
  const float* ew2 = (const float*)d_in[8],  *eb2 = (const float*)d_in[9];
  const float* p1w1 = (const float*)d_in[10], *p1b1 = (const float*)d_in[11];
  const float* p1w2 = (const float*)d_in[12], *p1b2 = (const float*)d_in[13];
  const float* p2w1 = (const float*)d_in[14], *p2b1 = (const float*)d_in[15];
  const float* p2w2 = (const float*)d_in[16], *p2b2 = (const float*)d_in[17];
  const float* p3w1 = (const float*)d_in[18], *p3b1 = (const float*)d_in[19];
  const float* p3w2 = (const float*)d_in[20], *p3b2 = (const float*)d_in[21];
  const float* ignw = (const float*)d_in[22], *ignb = (const float*)d_in[23];
  const float* cw1 = (const float*)d_in[24], *cb1 = (const float*)d_in[25];
  const float* cw2 = (const float*)d_in[26];
  const float* ndw1 = (const float*)d_in[27], *ndb1 = (const float*)d_in[28];
  const float* ndw2 = (const float*)d_in[29], *ndb2 = (const float*)d_in[30];

  // ---- workspace layout (~162 MB) ----
  char* ws = (char*)d_ws;
  __hip_bfloat16* D1d  = (__hip_bfloat16*)(ws + 0);          // [64][512][512] = 33,554,432 B
  __hip_bfloat16* S    = (__hip_bfloat16*)(ws + 0);          // cell-major S aliases dead D1d
  __hip_bfloat16* D2dT = (__hip_bfloat16*)(ws + 33554432);   // 33,554,432 B
  __hip_bfloat16* S_fij = (__hip_bfloat16*)(ws + 67108864);  // 33,554,432 B
  float* row_part = (float*)(ws + 100663296);                // [32][512][128] = 8,388,608 B
  float* col_part = (float*)(ws + 117440512);                // [32][512][128]
  // ---- single zero-memset block [134,217,728 .. 140,910,608) ----
  float* Tc    = (float*)(ws + 134217728);                   // [16384][96] = 6,291,456 B
  int*   nC    = (int*)(ws + 140509184);                     // 1 int (+pad to 16)
  float* A     = (float*)(ws + 140509200);                   // 32768 floats
  float* B     = (float*)(ws + 140640272);                   // 32768 floats
  float* seg   = (float*)(ws + 140771344);                   // 1536 floats
  float* cnt   = (float*)(ws + 140777488);                   // 512 floats
  float* nb_t0 = (float*)(ws + 140779536);                   // 32768 floats -> end 140,910,608
  // ---- rest ----
  int*   slotmap  = (int*)(ws + 140910608);                  // 262144 ints (0xFF)
  int*   slotmapT = (int*)(ws + 141959184);                  // 262144 ints (0xFF)
  int*   cells    = (int*)(ws + 143007760);                  // 16384 ints
  float* D1       = (float*)(ws + 143073296);                // [16384][64]
  float* D2       = (float*)(ws + 147267600);                // [16384][64]
  float* TWc      = (float*)(ws + 151461904);                // [16384][128]
  float* c1       = (float*)(ws + 159850512);                // 64
  float* c2       = (float*)(ws + 159850768);                // 64
  float* u        = (float*)(ws + 159851024);                // [512][128]
  float* v        = (float*)(ws + 160113168);                // [512][128]
  float* coord_diff  = (float*)(ws + 160375312);             // [512][3]
  float* efn         = (float*)(ws + 160381456);             // [512][64]
  float* diag_silu   = (float*)(ws + 160512528);             // [512][128]
  float* rowsum_silu = (float*)(ws + 160774672);
  float* colsum_silu = (float*)(ws + 161036816);
  float* diag_T      = (float*)(ws + 161298960);             // [512][64]
  float* row_T       = (float*)(ws + 161430032);
  float* col_T       = (float*)(ws + 161561104);
  float* tot         = (float*)(ws + 161692176);             // 64
  float* tr          = (float*)(ws + 161692432);             // 64
  float* nb_t1       = (float*)(ws + 161692688);             // [512][64]
  __hip_bfloat16* Wt = (__hip_bfloat16*)(ws + 161823760);    // [128][64] -> 161,840,144
  __hip_bfloat16* w11b = (__hip_bfloat16*)(ws + 161840144);  // [96][128]
  __hip_bfloat16* w21b = (__hip_bfloat16*)(ws + 161864720);  // [96][128]
  __hip_bfloat16* pw1b = (__hip_bfloat16*)(ws + 161889296);  // [96][128]
  __hip_bfloat16* w12b = (__hip_bfloat16*)(ws + 161913872);  // [128][64]
  __hip_bfloat16* w22b = (__hip_bfloat16*)(ws + 161930256);  // [128][64] -> end 161,946,640

  float* out_h  = (float*)d_out;
  float* out_x  = out_h + 512 * 64;
  float* out_ea = out_x + 512 * 3;

  hipMemsetAsync(slotmap, 0xFF, 2097152, stream);            // slotmap + slotmapT = -1
  hipMemsetAsync(ws + 134217728, 0, 6692880, stream);        // Tc..nb_t0

  k_edge<<<512, 128, 0, stream>>>(h, x, edges, ew1, eb1, ew2, eb2, coord_diff, efn);
  k_consts<<<1, 128, 0, stream>>>(p1b1, p1w2, p1b2, p2b1, p2w2, p2b2, c1, c2);
  k_prep<<<32, 256, 0, stream>>>(p3w1, Wt);
  k_prepw<<<208, 256, 0, stream>>>(p1w1, p2w1, p3w1, p1w2, p2w2,
                                   w11b, w21b, pw1b, w12b, w22b);
  k_mark<<<64, 256, 0, stream>>>(nb_edge, slotmap);
  k_compact<<<1024, 256, 0, stream>>>(slotmap, slotmapT, cells, nC);
  k_scatterT<<<8192, 192, 0, stream>>>(nb_edge, slotmap, coord_diff, efn, Tc);
  k_mlp96b<<<1024, 128, 0, stream>>>(cells, nC, Tc,
                                     w11b, p1b1, w12b, p1b2,
                                     w21b, p2b1, w22b, p2b2,
                                     c1, c2, pw1b, D1, D2, A, B, TWc);
  k_uv<<<dim3(512, 2), 128, 0, stream>>>(A, B, c1, c2, p3w1, p3b1, u, v);
  k_densify<<<dim3(512, 128), 512, 0, stream>>>(slotmap, slotmapT, D1, D2, D1d, D2dT);
  k_einsum_mfma<<<1024, 256, 0, stream>>>(D1d, D2dT, S_fij);
  k_transpose<<<4096, 256, 0, stream>>>(S_fij, S);
  k_tout_mfma<<<1024, 256, 0, stream>>>(S, u, v, TWc, slotmap, Wt,
                                        row_part, col_part, diag_silu);
  k_sumparts<<<512, 256, 0, stream>>>(row_part, col_part, rowsum_silu, colsum_silu);
  k_tout2<<<dim3(512, 3), 64, 0, stream>>>(diag_silu, rowsum_silu, colsum_silu,
                                           p3w2, p3b2, diag_T, row_T, col_T);
  k_totr<<<1, 128, 0, stream>>>(row_T, diag_T, tot, tr);
  k_nbt1<<<512, 64, 0, stream>>>(diag_T, row_T, col_T, tot, tr, ignw, ignb, nb_t1);
  k_edge_out<<<512, 128, 0, stream>>>(edges, coord_diff, nb_t1, edge_attr,
                                      cw1, cb1, cw2, seg, cnt, nb_t0, out_ea);
  k_node_out<<<512, 128, 0, stream>>>(h, x, seg, cnt, nb_t0,
                                      ndw1, ndb1, ndw2, ndb2, out_h, out_x);
}

// Round 14
// 456.755 us; speedup vs baseline: 1.0077x; 1.0077x over previous
//
#include <hip/hip_runtime.h>
#include <hip/hip_bf16.h>

// Problem constants (static per reference)
#define NN   512    // nodes
#define EE   512    // edges == nb-graph nodes (En)
#define MM   16384  // nb-graph edges

typedef float v4f __attribute__((ext_vector_type(4)));
typedef short short8v __attribute__((ext_vector_type(8)));

__device__ __forceinline__ float silu_f(float v) { return v / (1.0f + __expf(-v)); }

// ---------------- K1: per original edge: coord_diff + efn = MLP([h_r|h_c]) ----
__global__ __launch_bounds__(128) void k_edge(
    const float* __restrict__ h, const float* __restrict__ x,
    const int* __restrict__ edges,
    const float* __restrict__ ew1, const float* __restrict__ eb1,
    const float* __restrict__ ew2, const float* __restrict__ eb2,
    float* __restrict__ coord_diff, float* __restrict__ efn) {
  __shared__ float hin[128];
  __shared__ float hs[128];
  int e = blockIdx.x;
  int t = threadIdx.x;
  int r = edges[e], c = edges[EE + e];
  if (t < 3) coord_diff[e * 3 + t] = x[r * 3 + t] - x[c * 3 + t];
  if (t < 64) { hin[t] = h[r * 64 + t]; hin[64 + t] = h[c * 64 + t]; }
  __syncthreads();
  float acc = eb1[t];
  for (int k = 0; k < 128; ++k) acc += hin[k] * ew1[k * 128 + t];
  hs[t] = silu_f(acc);
  __syncthreads();
  if (t < 64) {
    float o = eb2[t];
    for (int k = 0; k < 128; ++k) o += hs[k] * ew2[k * 64 + t];
    efn[e * 64 + t] = o;
  }
}

// ---------------- K2: constants c1 = MLP1(0), c2 = MLP2(0) -------------------
__global__ __launch_bounds__(128) void k_consts(
    const float* __restrict__ p1b1, const float* __restrict__ p1w2, const float* __restrict__ p1b2,
    const float* __restrict__ p2b1, const float* __restrict__ p2w2, const float* __restrict__ p2b2,
    float* __restrict__ c1, float* __restrict__ c2) {
  __shared__ float h1[128], h2[128];
  int t = threadIdx.x;
  h1[t] = silu_f(p1b1[t]); h2[t] = silu_f(p2b1[t]);
  __syncthreads();
  if (t < 64) {
    float a1 = p1b2[t], a2 = p2b2[t];
    for (int k = 0; k < 128; ++k) { a1 += h1[k] * p1w2[k * 64 + t]; a2 += h2[k] * p2w2[k * 64 + t]; }
    c1[t] = a1; c2[t] = a2;
  }
}

// ---------------- K2b: Wt[h][f] = bf16(p3w1[96+f][h]) (B-operand for MFMA) ---
__global__ __launch_bounds__(256) void k_prep(const float* __restrict__ p3w1,
                                              __hip_bfloat16* __restrict__ Wt) {
  int e = blockIdx.x * 256 + threadIdx.x;   // 8192 = 128 h x 64 f
  int hh = e >> 6, f = e & 63;
  Wt[hh * 64 + f] = __float2bfloat16(p3w1[(96 + f) * 128 + hh]);
}

// ---------------- K3: mark touched cells -------------------------------------
__global__ __launch_bounds__(256) void k_mark(const int* __restrict__ nb_edge,
                                              int* __restrict__ slotmap) {
  int m = blockIdx.x * 256 + threadIdx.x;
  if (m >= MM) return;
  int cell = nb_edge[m] * 512 + nb_edge[MM + m];
  atomicCAS(&slotmap[cell], -1, -2);
}

// ------ K4: compact marked cells -> slots (both orientations) ----------------
__global__ __launch_bounds__(256) void k_compact(int* __restrict__ slotmap,
                                                 int* __restrict__ slotmapT,
                                                 int* __restrict__ cells,
                                                 int* __restrict__ nC) {
  int cell = blockIdx.x * 256 + threadIdx.x;
  if (slotmap[cell] != -2) return;
  int s = atomicAdd(nC, 1);
  slotmap[cell] = s;
  slotmapT[(cell & 511) * 512 + (cell >> 9)] = s;
  cells[s] = cell;
}

// ---------------- K7: nb_feat scatter-add into COMPACT Tc (2 edges/block) ----
__global__ __launch_bounds__(192) void k_scatterT(
    const int* __restrict__ nb_edge, const int* __restrict__ slotmap,
    const float* __restrict__ coord_diff, const float* __restrict__ efn,
    float* __restrict__ Tc) {
  int t = threadIdx.x;
  int sub = (t >= 96) ? 1 : 0;
  int c = t - sub * 96;
  int m = blockIdx.x * 2 + sub;
  int a = nb_edge[m], b = nb_edge[MM + m];
  int s = slotmap[a * 512 + b];
  float val;
  if (c < 32) {
    float vtv = coord_diff[a * 3 + 0] * coord_diff[b * 3 + 0]
              + coord_diff[a * 3 + 1] * coord_diff[b * 3 + 1]
              + coord_diff[a * 3 + 2] * coord_diff[b * 3 + 2];
    int i = c >> 1;
    float ang = vtv * 16.0f * __expf(-0.57564627324851143f * (float)i);
    val = (c & 1) ? cosf(ang) : sinf(ang);
  } else {
    int f = c - 32;
    val = efn[a * 64 + f] * efn[b * 64 + f];
  }
  atomicAdd(&Tc[s * 96 + c], val);
}

// ------- K8: batched (8 cells/block) MLPs -> D1/D2, sums A,B; TWc = Tc@w1T ---
__global__ __launch_bounds__(128) void k_mlp96b(
    const int* __restrict__ cells, const int* __restrict__ nC, const float* __restrict__ Tc,
    const float* __restrict__ w11, const float* __restrict__ b11,
    const float* __restrict__ w12, const float* __restrict__ b12,
    const float* __restrict__ w21, const float* __restrict__ b21,
    const float* __restrict__ w22, const float* __restrict__ b22,
    const float* __restrict__ c1, const float* __restrict__ c2,
    const float* __restrict__ p3w1,
    float* __restrict__ D1, float* __restrict__ D2,
    float* __restrict__ A, float* __restrict__ B,
    float* __restrict__ TWc) {
  __shared__ float xsT[96 * 8];    // [k][cell] transposed for b128 reads
  __shared__ float hid[8][128];
  __shared__ int cl[8];
  int t = threadIdx.x;
  int nc = *nC;
  int s0 = blockIdx.x * 8;
  if (s0 >= nc) return;
  for (int e = t; e < 768; e += 128) xsT[(e % 96) * 8 + e / 96] = Tc[s0 * 96 + e];
  if (t < 8) cl[t] = (s0 + t < nc) ? cells[s0 + t] : 0;
  __syncthreads();
  float tw[8], a1[8], a2[8];
#pragma unroll
  for (int c = 0; c < 8; ++c) { tw[c] = 0.f; a1[c] = b11[t]; a2[c] = b21[t]; }
  for (int k = 0; k < 96; ++k) {
    float wt = p3w1[k * 128 + t];
    float w1v = w11[k * 128 + t];
    float w2v = w21[k * 128 + t];
    float4 xlo = *(const float4*)&xsT[k * 8];
    float4 xhi = *(const float4*)&xsT[k * 8 + 4];
    float xv[8] = {xlo.x, xlo.y, xlo.z, xlo.w, xhi.x, xhi.y, xhi.z, xhi.w};
#pragma unroll
    for (int c = 0; c < 8; ++c) {
      tw[c] += xv[c] * wt; a1[c] += xv[c] * w1v; a2[c] += xv[c] * w2v;
    }
  }
#pragma unroll
  for (int c = 0; c < 8; ++c) {
    if (s0 + c < nc) TWc[(s0 + c) * 128 + t] = tw[c];
    hid[c][t] = silu_f(a1[c]);
  }
  __syncthreads();
  {
    int hh = t & 63, cq = t >> 6;
    float o[4];
#pragma unroll
    for (int cc = 0; cc < 4; ++cc) o[cc] = b12[hh];
    for (int k = 0; k < 128; ++k) {
      float w = w12[k * 64 + hh];
#pragma unroll
      for (int cc = 0; cc < 4; ++cc) o[cc] += hid[cq * 4 + cc][k] * w;
    }
#pragma unroll
    for (int cc = 0; cc < 4; ++cc) {
      int c = cq * 4 + cc;
      if (s0 + c < nc) {
        float d = o[cc] - c1[hh];
        D1[(s0 + c) * 64 + hh] = d;
        atomicAdd(&A[(cl[c] >> 9) * 64 + hh], d);
      }
    }
  }
  __syncthreads();
#pragma unroll
  for (int c = 0; c < 8; ++c) hid[c][t] = silu_f(a2[c]);
  __syncthreads();
  {
    int hh = t & 63, cq = t >> 6;
    float o[4];
#pragma unroll
    for (int cc = 0; cc < 4; ++cc) o[cc] = b22[hh];
    for (int k = 0; k < 128; ++k) {
      float w = w22[k * 64 + hh];
#pragma unroll
      for (int cc = 0; cc < 4; ++cc) o[cc] += hid[cq * 4 + cc][k] * w;
    }
#pragma unroll
    for (int cc = 0; cc < 4; ++cc) {
      int c = cq * 4 + cc;
      if (s0 + c < nc) {
        float d = o[cc] - c2[hh];
        D2[(s0 + c) * 64 + hh] = d;
        atomicAdd(&B[(cl[c] & 511) * 64 + hh], d);
      }
    }
  }
}

// ---------------- K10: u[i] = b1 + (512 c1c2 + c2*A[i])@w1m ; v[j] = (c1*B[j])@w1m
__global__ __launch_bounds__(128) void k_uv(
    const float* __restrict__ A, const float* __restrict__ B,
    const float* __restrict__ c1, const float* __restrict__ c2,
    const float* __restrict__ p3w1, const float* __restrict__ p3b1,
    float* __restrict__ u, float* __restrict__ v) {
  __shared__ float vec[64];
  int i = blockIdx.x, y = blockIdx.y, t = threadIdx.x;
  if (t < 64)
    vec[t] = (y == 0) ? (512.0f * c1[t] * c2[t] + c2[t] * A[i * 64 + t])
                      : (c1[t] * B[i * 64 + t]);
  __syncthreads();
  float a = (y == 0) ? p3b1[t] : 0.f;
  for (int f = 0; f < 64; ++f) a += vec[f] * p3w1[(96 + f) * 128 + t];
  (y == 0 ? u : v)[i * 128 + t] = a;
}

// ------- K10b: transpose D1/D2 [16384][64] fp32 -> D1T/D2T [64][16384] bf16 --
__global__ __launch_bounds__(256) void k_dtrans(
    const float* __restrict__ D1, const float* __restrict__ D2,
    __hip_bfloat16* __restrict__ D1T, __hip_bfloat16* __restrict__ D2T) {
  __shared__ float tile[64][65];
  int t = threadIdx.x;
  int s0 = blockIdx.x * 64;
  const float* src = blockIdx.y ? D2 : D1;
  __hip_bfloat16* dst = blockIdx.y ? D2T : D1T;
#pragma unroll 4
  for (int p = 0; p < 16; ++p) {
    int row = p * 4 + (t >> 6), f = t & 63;
    tile[row][f] = src[(s0 + row) * 64 + f];
  }
  __syncthreads();
#pragma unroll 4
  for (int p = 0; p < 16; ++p) {
    int f = p * 4 + (t >> 6), so = t & 63;
    dst[f * 16384 + s0 + so] = __float2bfloat16(tile[so][f]);
  }
}

// ---------------- K11a: densify into plane-major bf16, gathering from --------
// L1-resident 32KB bf16 planes D1T/D2T (pure 2B copy, no conversion).
__global__ __launch_bounds__(512) void k_densify(
    const int* __restrict__ slotmap, const int* __restrict__ slotmapT,
    const __hip_bfloat16* __restrict__ D1T, const __hip_bfloat16* __restrict__ D2T,
    __hip_bfloat16* __restrict__ D1d, __hip_bfloat16* __restrict__ D2dT) {
  int k = threadIdx.x;
  int i = blockIdx.x;
  int y = blockIdx.y;
  const int* sm = (y < 64) ? slotmap : slotmapT;
  const unsigned short* srcT =
      (const unsigned short*)((y < 64) ? D1T : D2T);
  unsigned short* dst = (unsigned short*)((y < 64) ? D1d : D2dT);
  int f = y & 63;
  int s = sm[i * 512 + k];
  unsigned short v = (s >= 0) ? srcT[f * 16384 + s] : (unsigned short)0;
  dst[(f * 512 + i) * 512 + k] = v;
}

// ---------------- K11b: batched plane GEMM S_f = A_f * B_f (MFMA) ------------
__global__ __launch_bounds__(256) void k_einsum_mfma(
    const __hip_bfloat16* __restrict__ D1d,
    const __hip_bfloat16* __restrict__ D2dT,
    __hip_bfloat16* __restrict__ S_fij) {
  __shared__ short As[128 * 40];
  __shared__ short Bs[128 * 40];
  int b = blockIdx.x;
  int f = b >> 4;
  int i0 = ((b >> 2) & 3) * 128, j0 = (b & 3) * 128;
  int t = threadIdx.x;
  int w = t >> 6, lane = t & 63;
  int wy = w >> 1, wx = w & 1;
  int q = lane >> 4, l15 = lane & 15;
  const short* Ap = (const short*)D1d + f * 262144;
  const short* Bp = (const short*)D2dT + f * 262144;
  int row = t >> 1, seg = t & 1;   // staging: 128 rows x 2 segments of 16
  v4f acc[4][4];
#pragma unroll
  for (int yi = 0; yi < 4; ++yi)
#pragma unroll
    for (int xj = 0; xj < 4; ++xj) acc[yi][xj] = (v4f){0.f, 0.f, 0.f, 0.f};
  for (int k0 = 0; k0 < 512; k0 += 32) {
    __syncthreads();
    const short8v* ga = (const short8v*)&Ap[(i0 + row) * 512 + k0 + seg * 16];
    const short8v* gb = (const short8v*)&Bp[(j0 + row) * 512 + k0 + seg * 16];
    *(short8v*)&As[row * 40 + seg * 16] = ga[0];
    *(short8v*)&As[row * 40 + seg * 16 + 8] = ga[1];
    *(short8v*)&Bs[row * 40 + seg * 16] = gb[0];
    *(short8v*)&Bs[row * 40 + seg * 16 + 8] = gb[1];
    __syncthreads();
    short8v af[4], bf[4];
#pragma unroll
    for (int x = 0; x < 4; ++x) {
      af[x] = *(const short8v*)&As[(wy * 64 + x * 16 + l15) * 40 + q * 8];
      bf[x] = *(const short8v*)&Bs[(wx * 64 + x * 16 + l15) * 40 + q * 8];
    }
#pragma unroll
    for (int yi = 0; yi < 4; ++yi)
#pragma unroll
      for (int xj = 0; xj < 4; ++xj)
        acc[yi][xj] = __builtin_amdgcn_mfma_f32_16x16x32_bf16(af[yi], bf[xj], acc[yi][xj], 0, 0, 0);
  }
  // C layout: col j = l15, row i = q*4 + r  [m89-verified]
#pragma unroll
  for (int yi = 0; yi < 4; ++yi)
#pragma unroll
    for (int r = 0; r < 4; ++r) {
      int irow = i0 + wy * 64 + yi * 16 + q * 4 + r;
#pragma unroll
      for (int xj = 0; xj < 4; ++xj)
        S_fij[(f * 512 + irow) * 512 + j0 + wx * 64 + xj * 16 + l15] =
            __float2bfloat16(acc[yi][xj][r]);
    }
}

// ---------------- K11c: transpose S_fij [64][262144] -> S [262144][64] -------
__global__ __launch_bounds__(256) void k_transpose(
    const __hip_bfloat16* __restrict__ S_fij, __hip_bfloat16* __restrict__ S) {
  __shared__ short lds[64 * 72];
  int t = threadIdx.x;
  int ij0 = blockIdx.x * 64;
  const short* src = (const short*)S_fij;
#pragma unroll
  for (int p = 0; p < 2; ++p) {
    int f = p * 32 + (t >> 3), seg = t & 7;
    short8v ga = *(const short8v*)&src[f * 262144 + ij0 + seg * 8];
    int fgrp = f >> 3, flo = f & 7;
#pragma unroll
    for (int k = 0; k < 8; ++k) {
      int ij = seg * 8 + k;
      int swz = (fgrp ^ (ij & 7) ^ ((ij >> 3) & 7)) & 7;
      lds[ij * 72 + swz * 8 + flo] = ga[k];
    }
  }
  __syncthreads();
  short* dst = (short*)S;
#pragma unroll
  for (int p = 0; p < 2; ++p) {
    int ij = p * 32 + (t >> 3), fseg = t & 7;
    int swz = (fseg ^ (ij & 7) ^ ((ij >> 3) & 7)) & 7;
    short8v val = *(const short8v*)&lds[ij * 72 + swz * 8];
    *(short8v*)&dst[(ij0 + ij) * 64 + fseg * 8] = val;
  }
}

// ------- K12: MFMA z = S@Wt + u[i]+v[j]+TW, silu, row/col/diag reduce --------
// v3.1: 16x16-cell tile (grid 1024); bf16 uvL/colbuf -> 45.5 KB LDS.
// C layout [m89]: n(h) = l15, m = q*4+r -> jL = q*4+r, iL fixed per M-tile.
__global__ __launch_bounds__(256) void k_tout_mfma(
    const __hip_bfloat16* __restrict__ S, const float* __restrict__ u,
    const float* __restrict__ v, const float* __restrict__ TWc,
    const int* __restrict__ slotmap, const __hip_bfloat16* __restrict__ Wt,
    float* __restrict__ row_part, float* __restrict__ col_part,
    float* __restrict__ diag_silu) {
  __shared__ __hip_bfloat16 WtL[128 * 72];         // 18,432 B
  __shared__ __hip_bfloat16 uvL[4096];             // 8,192 B (u 16x128 | v 16x128)
  __shared__ __hip_bfloat16 colbuf[4][16][140];    // 17,920 B
  __shared__ int slotL[256];
  int t = threadIdx.x;
  int w = t >> 6, lane = t & 63;
  int q = lane >> 4, l15 = lane & 15;
  int bi = blockIdx.x >> 5, bj = blockIdx.x & 31;
  int i0 = bi * 16, j0 = bj * 16;
  for (int e = t; e < 4096; e += 256) {
    int row = e >> 5, c2 = e & 31;
    ((unsigned*)WtL)[row * 36 + c2] = ((const unsigned*)Wt)[row * 32 + c2];
  }
  for (int e = t; e < 2048; e += 256)
    uvL[e] = __float2bfloat16(u[(i0 + (e >> 7)) * 128 + (e & 127)]);
  for (int e = t; e < 2048; e += 256)
    uvL[2048 + e] = __float2bfloat16(v[(j0 + (e >> 7)) * 128 + (e & 127)]);
  slotL[t] = slotmap[(i0 + (t >> 4)) * 512 + j0 + (t & 15)];
  short8v a[4][2];
#pragma unroll
  for (int mt = 0; mt < 4; ++mt) {
    const short8v* sp =
        (const short8v*)&S[((i0 + w * 4 + mt) * 512 + j0 + l15) * 64];
    a[mt][0] = sp[q];
    a[mt][1] = sp[4 + q];
  }
  __syncthreads();
#pragma unroll
  for (int half = 0; half < 2; ++half) {
    v4f acc[4][4];
#pragma unroll
    for (int mt = 0; mt < 4; ++mt)
#pragma unroll
      for (int n4 = 0; n4 < 4; ++n4) {
        int nt = half * 4 + n4;
        const short8v* b0 = (const short8v*)&WtL[(nt * 16 + l15) * 72 + q * 8];
        const short8v* b1 = (const short8v*)&WtL[(nt * 16 + l15) * 72 + 32 + q * 8];
        v4f c = {0.f, 0.f, 0.f, 0.f};
        c = __builtin_amdgcn_mfma_f32_16x16x32_bf16(a[mt][0], *b0, c, 0, 0, 0);
        c = __builtin_amdgcn_mfma_f32_16x16x32_bf16(a[mt][1], *b1, c, 0, 0, 0);
        acc[mt][n4] = c;
      }
#pragma unroll
    for (int n4 = 0; n4 < 4; ++n4) {
      int nt = half * 4 + n4;
      int hh = nt * 16 + l15;
      float rs[4] = {0.f, 0.f, 0.f, 0.f};
#pragma unroll
      for (int r = 0; r < 4; ++r) {
        int jL = q * 4 + r;
        float cs = 0.f;
        float vv = __bfloat162float(uvL[2048 + jL * 128 + hh]);
#pragma unroll
        for (int mt = 0; mt < 4; ++mt) {
          int iL = w * 4 + mt;
          float z = acc[mt][n4][r] + __bfloat162float(uvL[iL * 128 + hh]) + vv;
          int s = slotL[iL * 16 + jL];
          if (s >= 0) z += TWc[s * 128 + hh];
          float sv = silu_f(z);
          rs[mt] += sv;
          cs += sv;
          if (bi == bj && iL == jL) diag_silu[(i0 + iL) * 128 + hh] = sv;
        }
        colbuf[w][jL][hh] = __float2bfloat16(cs);
      }
#pragma unroll
      for (int mt = 0; mt < 4; ++mt) {
        float rsum = rs[mt];
        rsum += __shfl_xor(rsum, 16);
        rsum += __shfl_xor(rsum, 32);
        if (q == 0)
          row_part[(bj * 512 + i0 + w * 4 + mt) * 128 + hh] = rsum;
      }
    }
  }
  __syncthreads();
  for (int e = t; e < 2048; e += 256) {
    int jL = e >> 7, hh = e & 127;
    float acc4 = __bfloat162float(colbuf[0][jL][hh]) + __bfloat162float(colbuf[1][jL][hh]) +
                 __bfloat162float(colbuf[2][jL][hh]) + __bfloat162float(colbuf[3][jL][hh]);
    col_part[(bi * 512 + j0 + jL) * 128 + hh] = acc4;
  }
}

// ---------------- K13: reduce 32 partial slices ------------------------------
__global__ __launch_bounds__(256) void k_sumparts(
    const float* __restrict__ row_part, const float* __restrict__ col_part,
    float* __restrict__ rowsum, float* __restrict__ colsum) {
  int i = blockIdx.x, t = threadIdx.x;
  const float* src = (t < 128) ? row_part : col_part;
  float* dst = (t < 128) ? rowsum : colsum;
  int hc = t & 127;
  float a = 0.f;
  for (int p = 0; p < 32; ++p) a += src[(p * 512 + i) * 128 + hc];
  dst[i * 128 + hc] = a;
}

// ---------------- K14: second layer of p3 MLP on reduced silu sums -----------
__global__ __launch_bounds__(64) void k_tout2(
    const float* __restrict__ diag_silu, const float* __restrict__ rowsum_silu,
    const float* __restrict__ colsum_silu,
    const float* __restrict__ w2, const float* __restrict__ b2,
    float* __restrict__ diag_T, float* __restrict__ row_T, float* __restrict__ col_T) {
  __shared__ float in[128];
  int e = blockIdx.x, which = blockIdx.y, t = threadIdx.x;
  const float* src = (which == 0) ? diag_silu : (which == 1) ? rowsum_silu : colsum_silu;
  in[t] = src[e * 128 + t]; in[64 + t] = src[e * 128 + 64 + t];
  __syncthreads();
  float a = 0.f;
  for (int k = 0; k < 128; ++k) a += in[k] * w2[k * 64 + t];
  float bias = b2[t] * ((which == 0) ? 1.0f : 512.0f);
  float* dst = (which == 0) ? diag_T : (which == 1) ? row_T : col_T;
  dst[e * 64 + t] = a + bias;
}

// ---------------- K15: tot / tr ----------------------------------------------
__global__ __launch_bounds__(128) void k_totr(
    const float* __restrict__ row_T, const float* __restrict__ diag_T,
    float* __restrict__ tot, float* __restrict__ tr) {
  int t = threadIdx.x;
  const float* src = (t < 64) ? row_T : diag_T;
  int f = t & 63;
  float a = 0.f;
  for (int e = 0; e < 512; ++e) a += src[e * 64 + f];
  if (t < 64) tot[f] = a; else tr[f] = a;
}

// ---------------- K16: nb_t1 = [diag|row|col|tot|tr] @ ign_w + ign_b ---------
__global__ __launch_bounds__(64) void k_nbt1(
    const float* __restrict__ diag_T, const float* __restrict__ row_T,
    const float* __restrict__ col_T, const float* __restrict__ tot,
    const float* __restrict__ tr,
    const float* __restrict__ gw, const float* __restrict__ gb,
    float* __restrict__ nb_t1) {
  __shared__ float in[320];
  int e = blockIdx.x, t = threadIdx.x;
  in[t] = diag_T[e * 64 + t]; in[64 + t] = row_T[e * 64 + t];
  in[128 + t] = col_T[e * 64 + t]; in[192 + t] = tot[t]; in[256 + t] = tr[t];
  __syncthreads();
  float a = gb[t];
  for (int k = 0; k < 320; ++k) a += in[k] * gw[k * 64 + t];
  nb_t1[e * 64 + t] = a;
}

// ----- K17: coord weight w_e, seg/cnt/nb_t0 scatters, edge_attr passthrough --
__global__ __launch_bounds__(128) void k_edge_out(
    const int* __restrict__ edges, const float* __restrict__ coord_diff,
    const float* __restrict__ nb_t1, const float* __restrict__ edge_attr,
    const float* __restrict__ cw1, const float* __restrict__ cb1,
    const float* __restrict__ cw2,
    float* __restrict__ seg, float* __restrict__ cnt, float* __restrict__ nb_t0,
    float* __restrict__ out_ea) {
  __shared__ float in[64];
  __shared__ float red[128];
  int e = blockIdx.x, t = threadIdx.x;
  if (t < 64) in[t] = nb_t1[e * 64 + t];
  __syncthreads();
  float a = cb1[t];
  for (int k = 0; k < 64; ++k) a += in[k] * cw1[k * 128 + t];
  red[t] = silu_f(a) * cw2[t];
  __syncthreads();
  for (int s2 = 64; s2 > 0; s2 >>= 1) {
    if (t < s2) red[t] += red[t + s2];
    __syncthreads();
  }
  float w = red[0];
  int r = edges[e];
  if (t < 3) atomicAdd(&seg[r * 3 + t], coord_diff[e * 3 + t] * w);
  if (t == 64) atomicAdd(&cnt[r], 1.0f);
  if (t < 64) atomicAdd(&nb_t0[r * 64 + t], in[t]);
  if (t < 4) out_ea[e * 4 + t] = edge_attr[e * 4 + t];
}

// ---------------- K18: x_new and h_new ---------------------------------------
__global__ __launch_bounds__(128) void k_node_out(
    const float* __restrict__ h, const float* __restrict__ x,
    const float* __restrict__ seg, const float* __restrict__ cnt,
    const float* __restrict__ nb_t0,
    const float* __restrict__ w1, const float* __restrict__ b1,
    const float* __restrict__ w2, const float* __restrict__ b2,
    float* __restrict__ out_h, float* __restrict__ out_x) {
  __shared__ float in[64];
  __shared__ float hs[128];
  int n = blockIdx.x, t = threadIdx.x;
  if (t < 3) {
    float c = cnt[n]; if (c < 1.f) c = 1.f;
    out_x[n * 3 + t] = x[n * 3 + t] + seg[n * 3 + t] / c;
  }
  if (t < 64) in[t] = nb_t0[n * 64 + t];
  __syncthreads();
  float a = b1[t];
  for (int k = 0; k < 64; ++k) a += in[k] * w1[k * 128 + t];
  hs[t] = silu_f(a);
  __syncthreads();
  if (t < 64) {
    float o = b2[t];
    for (int k = 0; k < 128; ++k) o += hs[k] * w2[k * 64 + t];
    out_h[n * 64 + t] = h[n * 64 + t] + o;
  }
}

extern "C" void kernel_launch(void* const* d_in, const int* in_sizes, int n_in,
                              void* d_out, int out_size, void* d_ws, size_t ws_size,
                              hipStream_t stream) {
  (void)in_sizes; (void)n_in; (void)out_size; (void)ws_size;
  const float* h  = (const float*)d_in[0];
  const float* x  = (const float*)d_in[1];
  const int* edges   = (const int*)d_in[2];
  const int* nb_edge = (const int*)d_in[3];
  const float* edge_attr = (const float*)d_in[4];
  const float* ew1 = (const float*)d_in[6],  *eb1 = (const float*)d_in[7];
  const float* ew2 = (const float*)d_in[8],  *eb2 = (const float*)d_in[9];
  const float* p1w1 = (const float*)d_in[10], *p1b1 = (const float*)d_in[11];
  const float* p1w2 = (const float*)d_in[12], *p1b2 = (const float*)d_in[13];
  const float* p2w1 = (const float*)d_in[14], *p2b1 = (const float*)d_in[15];
  const float* p2w2 = (const float*)d_in[16], *p2b2 = (const float*)d_in[17];
  const float* p3w1 = (const float*)d_in[18], *p3b1 = (const float*)d_in[19];
  const float* p3w2 = (const float*)d_in[20], *p3b2 = (const float*)d_in[21];
  const float* ignw = (const float*)d_in[22], *ignb = (const float*)d_in[23];
  const float* cw1 = (const float*)d_in[24], *cb1 = (const float*)d_in[25];
  const float* cw2 = (const float*)d_in[26];
  const float* ndw1 = (const float*)d_in[27], *ndb1 = (const float*)d_in[28];
  const float* ndw2 = (const float*)d_in[29], *ndb2 = (const float*)d_in[30];

  // ---- workspace layout (~166 MB) ----
  char* ws = (char*)d_ws;
  __hip_bfloat16* D1d  = (__hip_bfloat16*)(ws + 0);          // [64][512][512] = 33,554,432 B
  __hip_bfloat16* S    = (__hip_bfloat16*)(ws + 0);          // cell-major S aliases dead D1d
  __hip_bfloat16* D2dT = (__hip_bfloat16*)(ws + 33554432);   // 33,554,432 B
  __hip_bfloat16* S_fij = (__hip_bfloat16*)(ws + 67108864);  // 33,554,432 B
  float* row_part = (float*)(ws + 100663296);                // [32][512][128] = 8,388,608 B
  float* col_part = (float*)(ws + 117440512);                // [32][512][128]
  // ---- single zero-memset block [134,217,728 .. 140,910,608) ----
  float* Tc    = (float*)(ws + 134217728);                   // [16384][96] = 6,291,456 B
  int*   nC    = (int*)(ws + 140509184);                     // 1 int (+pad to 16)
  float* A     = (float*)(ws + 140509200);                   // 32768 floats
  float* B     = (float*)(ws + 140640272);                   // 32768 floats
  float* seg   = (float*)(ws + 140771344);                   // 1536 floats
  float* cnt   = (float*)(ws + 140777488);                   // 512 floats
  float* nb_t0 = (float*)(ws + 140779536);                   // 32768 floats -> end 140,910,608
  // ---- rest ----
  int*   slotmap  = (int*)(ws + 140910608);                  // 262144 ints (0xFF)
  int*   slotmapT = (int*)(ws + 141959184);                  // 262144 ints (0xFF)
  int*   cells    = (int*)(ws + 143007760);                  // 16384 ints
  float* D1       = (float*)(ws + 143073296);                // [16384][64]
  float* D2       = (float*)(ws + 147267600);                // [16384][64]
  float* TWc      = (float*)(ws + 151461904);                // [16384][128]
  float* c1       = (float*)(ws + 159850512);                // 64
  float* c2       = (float*)(ws + 159850768);                // 64
  float* u        = (float*)(ws + 159851024);                // [512][128]
  float* v        = (float*)(ws + 160113168);                // [512][128]
  float* coord_diff  = (float*)(ws + 160375312);             // [512][3]
  float* efn         = (float*)(ws + 160381456);             // [512][64]
  float* diag_silu   = (float*)(ws + 160512528);             // [512][128]
  float* rowsum_silu = (float*)(ws + 160774672);
  float* colsum_silu = (float*)(ws + 161036816);
  float* diag_T      = (float*)(ws + 161298960);             // [512][64]
  float* row_T       = (float*)(ws + 161430032);
  float* col_T       = (float*)(ws + 161561104);
  float* tot         = (float*)(ws + 161692176);             // 64
  float* tr          = (float*)(ws + 161692432);             // 64
  float* nb_t1       = (float*)(ws + 161692688);             // [512][64]
  __hip_bfloat16* Wt  = (__hip_bfloat16*)(ws + 161823760);   // [128][64] -> 161,840,144
  __hip_bfloat16* D1T = (__hip_bfloat16*)(ws + 161840144);   // [64][16384] = 2,097,152 B
  __hip_bfloat16* D2T = (__hip_bfloat16*)(ws + 163937296);   // -> end 166,034,448

  float* out_h  = (float*)d_out;
  float* out_x  = out_h + 512 * 64;
  float* out_ea = out_x + 512 * 3;

  hipMemsetAsync(slotmap, 0xFF, 2097152, stream);            // slotmap + slotmapT = -1
  hipMemsetAsync(ws + 134217728, 0, 6692880, stream);        // Tc..nb_t0

  k_edge<<<512, 128, 0, stream>>>(h, x, edges, ew1, eb1, ew2, eb2, coord_diff, efn);
  k_consts<<<1, 128, 0, stream>>>(p1b1, p1w2, p1b2, p2b1, p2w2, p2b2, c1, c2);
  k_prep<<<32, 256, 0, stream>>>(p3w1, Wt);
  k_mark<<<64, 256, 0, stream>>>(nb_edge, slotmap);
  k_compact<<<1024, 256, 0, stream>>>(slotmap, slotmapT, cells, nC);
  k_scatterT<<<8192, 192, 0, stream>>>(nb_edge, slotmap, coord_diff, efn, Tc);
  k_mlp96b<<<2048, 128, 0, stream>>>(cells, nC, Tc,
                                     p1w1, p1b1, p1w2, p1b2,
                                     p2w1, p2b1, p2w2, p2b2,
                                     c1, c2, p3w1, D1, D2, A, B, TWc);
  k_uv<<<dim3(512, 2), 128, 0, stream>>>(A, B, c1, c2, p3w1, p3b1, u, v);
  k_dtrans<<<dim3(256, 2), 256, 0, stream>>>(D1, D2, D1T, D2T);
  k_densify<<<dim3(512, 128), 512, 0, stream>>>(slotmap, slotmapT, D1T, D2T, D1d, D2dT);
  k_einsum_mfma<<<1024, 256, 0, stream>>>(D1d, D2dT, S_fij);
  k_transpose<<<4096, 256, 0, stream>>>(S_fij, S);
  k_tout_mfma<<<1024, 256, 0, stream>>>(S, u, v, TWc, slotmap, Wt,
                                        row_part, col_part, diag_silu);
  k_sumparts<<<512, 256, 0, stream>>>(row_part, col_part, rowsum_silu, colsum_silu);
  k_tout2<<<dim3(512, 3), 64, 0, stream>>>(diag_silu, rowsum_silu, colsum_silu,
                                           p3w2, p3b2, diag_T, row_T, col_T);
  k_totr<<<1, 128, 0, stream>>>(row_T, diag_T, tot, tr);
  k_nbt1<<<512, 64, 0, stream>>>(diag_T, row_T, col_T, tot, tr, ignw, ignb, nb_t1);
  k_edge_out<<<512, 128, 0, stream>>>(edges, coord_diff, nb_t1, edge_attr,
                                      cw1, cb1, cw2, seg, cnt, nb_t0, out_ea);
  k_node_out<<<512, 128, 0, stream>>>(h, x, seg, cnt, nb_t0,
                                      ndw1, ndb1, ndw2, ndb2, out_h, out_x);
}

// Round 15
// 414.320 us; speedup vs baseline: 1.1110x; 1.1024x over previous
//
#include <hip/hip_runtime.h>
#include <hip/hip_bf16.h>

// Problem constants (static per reference)
#define NN   512    // nodes
#define EE   512    // edges == nb-graph nodes (En)
#define MM   16384  // nb-graph edges

typedef float v4f __attribute__((ext_vector_type(4)));
typedef short short8v __attribute__((ext_vector_type(8)));

__device__ __forceinline__ float silu_f(float v) { return v / (1.0f + __expf(-v)); }

// ---------------- K1: per original edge: coord_diff + efn = MLP([h_r|h_c]) ----
__global__ __launch_bounds__(128) void k_edge(
    const float* __restrict__ h, const float* __restrict__ x,
    const int* __restrict__ edges,
    const float* __restrict__ ew1, const float* __restrict__ eb1,
    const float* __restrict__ ew2, const float* __restrict__ eb2,
    float* __restrict__ coord_diff, float* __restrict__ efn) {
  __shared__ float hin[128];
  __shared__ float hs[128];
  int e = blockIdx.x;
  int t = threadIdx.x;
  int r = edges[e], c = edges[EE + e];
  if (t < 3) coord_diff[e * 3 + t] = x[r * 3 + t] - x[c * 3 + t];
  if (t < 64) { hin[t] = h[r * 64 + t]; hin[64 + t] = h[c * 64 + t]; }
  __syncthreads();
  float acc = eb1[t];
  for (int k = 0; k < 128; ++k) acc += hin[k] * ew1[k * 128 + t];
  hs[t] = silu_f(acc);
  __syncthreads();
  if (t < 64) {
    float o = eb2[t];
    for (int k = 0; k < 128; ++k) o += hs[k] * ew2[k * 64 + t];
    efn[e * 64 + t] = o;
  }
}

// ---------------- K2: constants c1 = MLP1(0), c2 = MLP2(0) -------------------
__global__ __launch_bounds__(128) void k_consts(
    const float* __restrict__ p1b1, const float* __restrict__ p1w2, const float* __restrict__ p1b2,
    const float* __restrict__ p2b1, const float* __restrict__ p2w2, const float* __restrict__ p2b2,
    float* __restrict__ c1, float* __restrict__ c2) {
  __shared__ float h1[128], h2[128];
  int t = threadIdx.x;
  h1[t] = silu_f(p1b1[t]); h2[t] = silu_f(p2b1[t]);
  __syncthreads();
  if (t < 64) {
    float a1 = p1b2[t], a2 = p2b2[t];
    for (int k = 0; k < 128; ++k) { a1 += h1[k] * p1w2[k * 64 + t]; a2 += h2[k] * p2w2[k * 64 + t]; }
    c1[t] = a1; c2[t] = a2;
  }
}

// ---------------- K2b: Wt[h][f] = bf16(p3w1[96+f][h]) (B-operand for MFMA) ---
__global__ __launch_bounds__(256) void k_prep(const float* __restrict__ p3w1,
                                              __hip_bfloat16* __restrict__ Wt) {
  int e = blockIdx.x * 256 + threadIdx.x;   // 8192 = 128 h x 64 f
  int hh = e >> 6, f = e & 63;
  Wt[hh * 64 + f] = __float2bfloat16(p3w1[(96 + f) * 128 + hh]);
}

// ---------------- K3: mark touched cells -------------------------------------
__global__ __launch_bounds__(256) void k_mark(const int* __restrict__ nb_edge,
                                              int* __restrict__ slotmap) {
  int m = blockIdx.x * 256 + threadIdx.x;
  if (m >= MM) return;
  int cell = nb_edge[m] * 512 + nb_edge[MM + m];
  atomicCAS(&slotmap[cell], -1, -2);
}

// ------ K4: compact marked cells -> slots ------------------------------------
__global__ __launch_bounds__(256) void k_compact(int* __restrict__ slotmap,
                                                 int* __restrict__ cells,
                                                 int* __restrict__ nC) {
  int cell = blockIdx.x * 256 + threadIdx.x;
  if (slotmap[cell] != -2) return;
  int s = atomicAdd(nC, 1);
  slotmap[cell] = s;
  cells[s] = cell;
}

// ---------------- K7: nb_feat scatter-add into COMPACT Tc (2 edges/block) ----
__global__ __launch_bounds__(192) void k_scatterT(
    const int* __restrict__ nb_edge, const int* __restrict__ slotmap,
    const float* __restrict__ coord_diff, const float* __restrict__ efn,
    float* __restrict__ Tc) {
  int t = threadIdx.x;
  int sub = (t >= 96) ? 1 : 0;
  int c = t - sub * 96;
  int m = blockIdx.x * 2 + sub;
  int a = nb_edge[m], b = nb_edge[MM + m];
  int s = slotmap[a * 512 + b];
  float val;
  if (c < 32) {
    float vtv = coord_diff[a * 3 + 0] * coord_diff[b * 3 + 0]
              + coord_diff[a * 3 + 1] * coord_diff[b * 3 + 1]
              + coord_diff[a * 3 + 2] * coord_diff[b * 3 + 2];
    int i = c >> 1;
    float ang = vtv * 16.0f * __expf(-0.57564627324851143f * (float)i);
    val = (c & 1) ? cosf(ang) : sinf(ang);
  } else {
    int f = c - 32;
    val = efn[a * 64 + f] * efn[b * 64 + f];
  }
  atomicAdd(&Tc[s * 96 + c], val);
}

// ------- K8: batched (8 cells/block) MLPs; TWc = Tc@w1T; A/B sums; -----------
// fused DENSE-PLANE scatter of Delta1/Delta2 (bf16) -> no densify gather pass.
__global__ __launch_bounds__(128) void k_mlp96b(
    const int* __restrict__ cells, const int* __restrict__ nC, const float* __restrict__ Tc,
    const float* __restrict__ w11, const float* __restrict__ b11,
    const float* __restrict__ w12, const float* __restrict__ b12,
    const float* __restrict__ w21, const float* __restrict__ b21,
    const float* __restrict__ w22, const float* __restrict__ b22,
    const float* __restrict__ c1, const float* __restrict__ c2,
    const float* __restrict__ p3w1,
    __hip_bfloat16* __restrict__ D1d, __hip_bfloat16* __restrict__ D2dT,
    float* __restrict__ A, float* __restrict__ B,
    float* __restrict__ TWc) {
  __shared__ float xsT[96 * 8];    // [k][cell] transposed for b128 reads
  __shared__ float hid[8][128];
  __shared__ int cl[8];
  int t = threadIdx.x;
  int nc = *nC;
  int s0 = blockIdx.x * 8;
  if (s0 >= nc) return;
  for (int e = t; e < 768; e += 128) xsT[(e % 96) * 8 + e / 96] = Tc[s0 * 96 + e];
  if (t < 8) cl[t] = (s0 + t < nc) ? cells[s0 + t] : 0;
  __syncthreads();
  float tw[8], a1[8], a2[8];
#pragma unroll
  for (int c = 0; c < 8; ++c) { tw[c] = 0.f; a1[c] = b11[t]; a2[c] = b21[t]; }
  for (int k = 0; k < 96; ++k) {
    float wt = p3w1[k * 128 + t];
    float w1v = w11[k * 128 + t];
    float w2v = w21[k * 128 + t];
    float4 xlo = *(const float4*)&xsT[k * 8];
    float4 xhi = *(const float4*)&xsT[k * 8 + 4];
    float xv[8] = {xlo.x, xlo.y, xlo.z, xlo.w, xhi.x, xhi.y, xhi.z, xhi.w};
#pragma unroll
    for (int c = 0; c < 8; ++c) {
      tw[c] += xv[c] * wt; a1[c] += xv[c] * w1v; a2[c] += xv[c] * w2v;
    }
  }
#pragma unroll
  for (int c = 0; c < 8; ++c) {
    if (s0 + c < nc) TWc[(s0 + c) * 128 + t] = tw[c];
    hid[c][t] = silu_f(a1[c]);
  }
  __syncthreads();
  {
    int hh = t & 63, cq = t >> 6;
    float o[4];
#pragma unroll
    for (int cc = 0; cc < 4; ++cc) o[cc] = b12[hh];
    for (int k = 0; k < 128; ++k) {
      float w = w12[k * 64 + hh];
#pragma unroll
      for (int cc = 0; cc < 4; ++cc) o[cc] += hid[cq * 4 + cc][k] * w;
    }
#pragma unroll
    for (int cc = 0; cc < 4; ++cc) {
      int c = cq * 4 + cc;
      if (s0 + c < nc) {
        float d = o[cc] - c1[hh];
        int cell = cl[c];
        int ai = cell >> 9, bj = cell & 511;
        atomicAdd(&A[ai * 64 + hh], d);
        D1d[(hh * 512 + ai) * 512 + bj] = __float2bfloat16(d);   // plane f=hh
      }
    }
  }
  __syncthreads();
#pragma unroll
  for (int c = 0; c < 8; ++c) hid[c][t] = silu_f(a2[c]);
  __syncthreads();
  {
    int hh = t & 63, cq = t >> 6;
    float o[4];
#pragma unroll
    for (int cc = 0; cc < 4; ++cc) o[cc] = b22[hh];
    for (int k = 0; k < 128; ++k) {
      float w = w22[k * 64 + hh];
#pragma unroll
      for (int cc = 0; cc < 4; ++cc) o[cc] += hid[cq * 4 + cc][k] * w;
    }
#pragma unroll
    for (int cc = 0; cc < 4; ++cc) {
      int c = cq * 4 + cc;
      if (s0 + c < nc) {
        float d = o[cc] - c2[hh];
        int cell = cl[c];
        int ai = cell >> 9, bj = cell & 511;
        atomicAdd(&B[bj * 64 + hh], d);
        D2dT[(hh * 512 + bj) * 512 + ai] = __float2bfloat16(d);  // B^T plane
      }
    }
  }
}

// ---------------- K10: u[i] = b1 + (512 c1c2 + c2*A[i])@w1m ; v[j] = (c1*B[j])@w1m
__global__ __launch_bounds__(128) void k_uv(
    const float* __restrict__ A, const float* __restrict__ B,
    const float* __restrict__ c1, const float* __restrict__ c2,
    const float* __restrict__ p3w1, const float* __restrict__ p3b1,
    float* __restrict__ u, float* __restrict__ v) {
  __shared__ float vec[64];
  int i = blockIdx.x, y = blockIdx.y, t = threadIdx.x;
  if (t < 64)
    vec[t] = (y == 0) ? (512.0f * c1[t] * c2[t] + c2[t] * A[i * 64 + t])
                      : (c1[t] * B[i * 64 + t]);
  __syncthreads();
  float a = (y == 0) ? p3b1[t] : 0.f;
  for (int f = 0; f < 64; ++f) a += vec[f] * p3w1[(96 + f) * 128 + t];
  (y == 0 ? u : v)[i * 128 + t] = a;
}

// ---------------- K11b: batched plane GEMM S_f = A_f * B_f (MFMA) ------------
__global__ __launch_bounds__(256) void k_einsum_mfma(
    const __hip_bfloat16* __restrict__ D1d,
    const __hip_bfloat16* __restrict__ D2dT,
    __hip_bfloat16* __restrict__ S_fij) {
  __shared__ short As[128 * 40];
  __shared__ short Bs[128 * 40];
  int b = blockIdx.x;
  int f = b >> 4;
  int i0 = ((b >> 2) & 3) * 128, j0 = (b & 3) * 128;
  int t = threadIdx.x;
  int w = t >> 6, lane = t & 63;
  int wy = w >> 1, wx = w & 1;
  int q = lane >> 4, l15 = lane & 15;
  const short* Ap = (const short*)D1d + f * 262144;
  const short* Bp = (const short*)D2dT + f * 262144;
  int row = t >> 1, seg = t & 1;   // staging: 128 rows x 2 segments of 16
  v4f acc[4][4];
#pragma unroll
  for (int yi = 0; yi < 4; ++yi)
#pragma unroll
    for (int xj = 0; xj < 4; ++xj) acc[yi][xj] = (v4f){0.f, 0.f, 0.f, 0.f};
  for (int k0 = 0; k0 < 512; k0 += 32) {
    __syncthreads();
    const short8v* ga = (const short8v*)&Ap[(i0 + row) * 512 + k0 + seg * 16];
    const short8v* gb = (const short8v*)&Bp[(j0 + row) * 512 + k0 + seg * 16];
    *(short8v*)&As[row * 40 + seg * 16] = ga[0];
    *(short8v*)&As[row * 40 + seg * 16 + 8] = ga[1];
    *(short8v*)&Bs[row * 40 + seg * 16] = gb[0];
    *(short8v*)&Bs[row * 40 + seg * 16 + 8] = gb[1];
    __syncthreads();
    short8v af[4], bf[4];
#pragma unroll
    for (int x = 0; x < 4; ++x) {
      af[x] = *(const short8v*)&As[(wy * 64 + x * 16 + l15) * 40 + q * 8];
      bf[x] = *(const short8v*)&Bs[(wx * 64 + x * 16 + l15) * 40 + q * 8];
    }
#pragma unroll
    for (int yi = 0; yi < 4; ++yi)
#pragma unroll
      for (int xj = 0; xj < 4; ++xj)
        acc[yi][xj] = __builtin_amdgcn_mfma_f32_16x16x32_bf16(af[yi], bf[xj], acc[yi][xj], 0, 0, 0);
  }
  // C layout: col j = l15, row i = q*4 + r  [m89-verified]
#pragma unroll
  for (int yi = 0; yi < 4; ++yi)
#pragma unroll
    for (int r = 0; r < 4; ++r) {
      int irow = i0 + wy * 64 + yi * 16 + q * 4 + r;
#pragma unroll
      for (int xj = 0; xj < 4; ++xj)
        S_fij[(f * 512 + irow) * 512 + j0 + wx * 64 + xj * 16 + l15] =
            __float2bfloat16(acc[yi][xj][r]);
    }
}

// ---------------- K11c: transpose S_fij [64][262144] -> S [262144][64] -------
__global__ __launch_bounds__(256) void k_transpose(
    const __hip_bfloat16* __restrict__ S_fij, __hip_bfloat16* __restrict__ S) {
  __shared__ short lds[64 * 72];
  int t = threadIdx.x;
  int ij0 = blockIdx.x * 64;
  const short* src = (const short*)S_fij;
#pragma unroll
  for (int p = 0; p < 2; ++p) {
    int f = p * 32 + (t >> 3), seg = t & 7;
    short8v ga = *(const short8v*)&src[f * 262144 + ij0 + seg * 8];
    int fgrp = f >> 3, flo = f & 7;
#pragma unroll
    for (int k = 0; k < 8; ++k) {
      int ij = seg * 8 + k;
      int swz = (fgrp ^ (ij & 7) ^ ((ij >> 3) & 7)) & 7;
      lds[ij * 72 + swz * 8 + flo] = ga[k];
    }
  }
  __syncthreads();
  short* dst = (short*)S;
#pragma unroll
  for (int p = 0; p < 2; ++p) {
    int ij = p * 32 + (t >> 3), fseg = t & 7;
    int swz = (fseg ^ (ij & 7) ^ ((ij >> 3) & 7)) & 7;
    short8v val = *(const short8v*)&lds[ij * 72 + swz * 8];
    *(short8v*)&dst[(ij0 + ij) * 64 + fseg * 8] = val;
  }
}

// ------- K12: MFMA z = S@Wt + u[i]+v[j]+TW, silu, row/col/diag reduce --------
// v3.1: 16x16-cell tile (grid 1024); bf16 uvL/colbuf -> 45.5 KB LDS.
// C layout [m89]: n(h) = l15, m = q*4+r -> jL = q*4+r, iL fixed per M-tile.
__global__ __launch_bounds__(256) void k_tout_mfma(
    const __hip_bfloat16* __restrict__ S, const float* __restrict__ u,
    const float* __restrict__ v, const float* __restrict__ TWc,
    const int* __restrict__ slotmap, const __hip_bfloat16* __restrict__ Wt,
    float* __restrict__ row_part, float* __restrict__ col_part,
    float* __restrict__ diag_silu) {
  __shared__ __hip_bfloat16 WtL[128 * 72];         // 18,432 B
  __shared__ __hip_bfloat16 uvL[4096];             // 8,192 B (u 16x128 | v 16x128)
  __shared__ __hip_bfloat16 colbuf[4][16][140];    // 17,920 B
  __shared__ int slotL[256];
  int t = threadIdx.x;
  int w = t >> 6, lane = t & 63;
  int q = lane >> 4, l15 = lane & 15;
  int bi = blockIdx.x >> 5, bj = blockIdx.x & 31;
  int i0 = bi * 16, j0 = bj * 16;
  for (int e = t; e < 4096; e += 256) {
    int row = e >> 5, c2 = e & 31;
    ((unsigned*)WtL)[row * 36 + c2] = ((const unsigned*)Wt)[row * 32 + c2];
  }
  for (int e = t; e < 2048; e += 256)
    uvL[e] = __float2bfloat16(u[(i0 + (e >> 7)) * 128 + (e & 127)]);
  for (int e = t; e < 2048; e += 256)
    uvL[2048 + e] = __float2bfloat16(v[(j0 + (e >> 7)) * 128 + (e & 127)]);
  slotL[t] = slotmap[(i0 + (t >> 4)) * 512 + j0 + (t & 15)];
  short8v a[4][2];
#pragma unroll
  for (int mt = 0; mt < 4; ++mt) {
    const short8v* sp =
        (const short8v*)&S[((i0 + w * 4 + mt) * 512 + j0 + l15) * 64];
    a[mt][0] = sp[q];
    a[mt][1] = sp[4 + q];
  }
  __syncthreads();
#pragma unroll
  for (int half = 0; half < 2; ++half) {
    v4f acc[4][4];
#pragma unroll
    for (int mt = 0; mt < 4; ++mt)
#pragma unroll
      for (int n4 = 0; n4 < 4; ++n4) {
        int nt = half * 4 + n4;
        const short8v* b0 = (const short8v*)&WtL[(nt * 16 + l15) * 72 + q * 8];
        const short8v* b1 = (const short8v*)&WtL[(nt * 16 + l15) * 72 + 32 + q * 8];
        v4f c = {0.f, 0.f, 0.f, 0.f};
        c = __builtin_amdgcn_mfma_f32_16x16x32_bf16(a[mt][0], *b0, c, 0, 0, 0);
        c = __builtin_amdgcn_mfma_f32_16x16x32_bf16(a[mt][1], *b1, c, 0, 0, 0);
        acc[mt][n4] = c;
      }
#pragma unroll
    for (int n4 = 0; n4 < 4; ++n4) {
      int nt = half * 4 + n4;
      int hh = nt * 16 + l15;
      float rs[4] = {0.f, 0.f, 0.f, 0.f};
#pragma unroll
      for (int r = 0; r < 4; ++r) {
        int jL = q * 4 + r;
        float cs = 0.f;
        float vv = __bfloat162float(uvL[2048 + jL * 128 + hh]);
#pragma unroll
        for (int mt = 0; mt < 4; ++mt) {
          int iL = w * 4 + mt;
          float z = acc[mt][n4][r] + __bfloat162float(uvL[iL * 128 + hh]) + vv;
          int s = slotL[iL * 16 + jL];
          if (s >= 0) z += TWc[s * 128 + hh];
          float sv = silu_f(z);
          rs[mt] += sv;
          cs += sv;
          if (bi == bj && iL == jL) diag_silu[(i0 + iL) * 128 + hh] = sv;
        }
        colbuf[w][jL][hh] = __float2bfloat16(cs);
      }
#pragma unroll
      for (int mt = 0; mt < 4; ++mt) {
        float rsum = rs[mt];
        rsum += __shfl_xor(rsum, 16);
        rsum += __shfl_xor(rsum, 32);
        if (q == 0)
          row_part[(bj * 512 + i0 + w * 4 + mt) * 128 + hh] = rsum;
      }
    }
  }
  __syncthreads();
  for (int e = t; e < 2048; e += 256) {
    int jL = e >> 7, hh = e & 127;
    float acc4 = __bfloat162float(colbuf[0][jL][hh]) + __bfloat162float(colbuf[1][jL][hh]) +
                 __bfloat162float(colbuf[2][jL][hh]) + __bfloat162float(colbuf[3][jL][hh]);
    col_part[(bi * 512 + j0 + jL) * 128 + hh] = acc4;
  }
}

// ---------------- K13: reduce 32 partial slices ------------------------------
__global__ __launch_bounds__(256) void k_sumparts(
    const float* __restrict__ row_part, const float* __restrict__ col_part,
    float* __restrict__ rowsum, float* __restrict__ colsum) {
  int i = blockIdx.x, t = threadIdx.x;
  const float* src = (t < 128) ? row_part : col_part;
  float* dst = (t < 128) ? rowsum : colsum;
  int hc = t & 127;
  float a = 0.f;
  for (int p = 0; p < 32; ++p) a += src[(p * 512 + i) * 128 + hc];
  dst[i * 128 + hc] = a;
}

// ---------------- K14: second layer of p3 MLP on reduced silu sums -----------
__global__ __launch_bounds__(64) void k_tout2(
    const float* __restrict__ diag_silu, const float* __restrict__ rowsum_silu,
    const float* __restrict__ colsum_silu,
    const float* __restrict__ w2, const float* __restrict__ b2,
    float* __restrict__ diag_T, float* __restrict__ row_T, float* __restrict__ col_T) {
  __shared__ float in[128];
  int e = blockIdx.x, which = blockIdx.y, t = threadIdx.x;
  const float* src = (which == 0) ? diag_silu : (which == 1) ? rowsum_silu : colsum_silu;
  in[t] = src[e * 128 + t]; in[64 + t] = src[e * 128 + 64 + t];
  __syncthreads();
  float a = 0.f;
  for (int k = 0; k < 128; ++k) a += in[k] * w2[k * 64 + t];
  float bias = b2[t] * ((which == 0) ? 1.0f : 512.0f);
  float* dst = (which == 0) ? diag_T : (which == 1) ? row_T : col_T;
  dst[e * 64 + t] = a + bias;
}

// ---------------- K15: tot / tr ----------------------------------------------
__global__ __launch_bounds__(128) void k_totr(
    const float* __restrict__ row_T, const float* __restrict__ diag_T,
    float* __restrict__ tot, float* __restrict__ tr) {
  int t = threadIdx.x;
  const float* src = (t < 64) ? row_T : diag_T;
  int f = t & 63;
  float a = 0.f;
  for (int e = 0; e < 512; ++e) a += src[e * 64 + f];
  if (t < 64) tot[f] = a; else tr[f] = a;
}

// ---------------- K16: nb_t1 = [diag|row|col|tot|tr] @ ign_w + ign_b ---------
__global__ __launch_bounds__(64) void k_nbt1(
    const float* __restrict__ diag_T, const float* __restrict__ row_T,
    const float* __restrict__ col_T, const float* __restrict__ tot,
    const float* __restrict__ tr,
    const float* __restrict__ gw, const float* __restrict__ gb,
    float* __restrict__ nb_t1) {
  __shared__ float in[320];
  int e = blockIdx.x, t = threadIdx.x;
  in[t] = diag_T[e * 64 + t]; in[64 + t] = row_T[e * 64 + t];
  in[128 + t] = col_T[e * 64 + t]; in[192 + t] = tot[t]; in[256 + t] = tr[t];
  __syncthreads();
  float a = gb[t];
  for (int k = 0; k < 320; ++k) a += in[k] * gw[k * 64 + t];
  nb_t1[e * 64 + t] = a;
}

// ----- K17: coord weight w_e, seg/cnt/nb_t0 scatters, edge_attr passthrough --
__global__ __launch_bounds__(128) void k_edge_out(
    const int* __restrict__ edges, const float* __restrict__ coord_diff,
    const float* __restrict__ nb_t1, const float* __restrict__ edge_attr,
    const float* __restrict__ cw1, const float* __restrict__ cb1,
    const float* __restrict__ cw2,
    float* __restrict__ seg, float* __restrict__ cnt, float* __restrict__ nb_t0,
    float* __restrict__ out_ea) {
  __shared__ float in[64];
  __shared__ float red[128];
  int e = blockIdx.x, t = threadIdx.x;
  if (t < 64) in[t] = nb_t1[e * 64 + t];
  __syncthreads();
  float a = cb1[t];
  for (int k = 0; k < 64; ++k) a += in[k] * cw1[k * 128 + t];
  red[t] = silu_f(a) * cw2[t];
  __syncthreads();
  for (int s2 = 64; s2 > 0; s2 >>= 1) {
    if (t < s2) red[t] += red[t + s2];
    __syncthreads();
  }
  float w = red[0];
  int r = edges[e];
  if (t < 3) atomicAdd(&seg[r * 3 + t], coord_diff[e * 3 + t] * w);
  if (t == 64) atomicAdd(&cnt[r], 1.0f);
  if (t < 64) atomicAdd(&nb_t0[r * 64 + t], in[t]);
  if (t < 4) out_ea[e * 4 + t] = edge_attr[e * 4 + t];
}

// ---------------- K18: x_new and h_new ---------------------------------------
__global__ __launch_bounds__(128) void k_node_out(
    const float* __restrict__ h, const float* __restrict__ x,
    const float* __restrict__ seg, const float* __restrict__ cnt,
    const float* __restrict__ nb_t0,
    const float* __restrict__ w1, const float* __restrict__ b1,
    const float* __restrict__ w2, const float* __restrict__ b2,
    float* __restrict__ out_h, float* __restrict__ out_x) {
  __shared__ float in[64];
  __shared__ float hs[128];
  int n = blockIdx.x, t = threadIdx.x;
  if (t < 3) {
    float c = cnt[n]; if (c < 1.f) c = 1.f;
    out_x[n * 3 + t] = x[n * 3 + t] + seg[n * 3 + t] / c;
  }
  if (t < 64) in[t] = nb_t0[n * 64 + t];
  __syncthreads();
  float a = b1[t];
  for (int k = 0; k < 64; ++k) a += in[k] * w1[k * 128 + t];
  hs[t] = silu_f(a);
  __syncthreads();
  if (t < 64) {
    float o = b2[t];
    for (int k = 0; k < 128; ++k) o += hs[k] * w2[k * 64 + t];
    out_h[n * 64 + t] = h[n * 64 + t] + o;
  }
}

extern "C" void kernel_launch(void* const* d_in, const int* in_sizes, int n_in,
                              void* d_out, int out_size, void* d_ws, size_t ws_size,
                              hipStream_t stream) {
  (void)in_sizes; (void)n_in; (void)out_size; (void)ws_size;
  const float* h  = (const float*)d_in[0];
  const float* x  = (const float*)d_in[1];
  const int* edges   = (const int*)d_in[2];
  const int* nb_edge = (const int*)d_in[3];
  const float* edge_attr = (const float*)d_in[4];
  const float* ew1 = (const float*)d_in[6],  *eb1 = (const float*)d_in[7];
  const float* ew2 = (const float*)d_in[8],  *eb2 = (const float*)d_in[9];
  const float* p1w1 = (const float*)d_in[10], *p1b1 = (const float*)d_in[11];
  const float* p1w2 = (const float*)d_in[12], *p1b2 = (const float*)d_in[13];
  const float* p2w1 = (const float*)d_in[14], *p2b1 = (const float*)d_in[15];
  const float* p2w2 = (const float*)d_in[16], *p2b2 = (const float*)d_in[17];
  const float* p3w1 = (const float*)d_in[18], *p3b1 = (const float*)d_in[19];
  const float* p3w2 = (const float*)d_in[20], *p3b2 = (const float*)d_in[21];
  const float* ignw = (const float*)d_in[22], *ignb = (const float*)d_in[23];
  const float* cw1 = (const float*)d_in[24], *cb1 = (const float*)d_in[25];
  const float* cw2 = (const float*)d_in[26];
  const float* ndw1 = (const float*)d_in[27], *ndb1 = (const float*)d_in[28];
  const float* ndw2 = (const float*)d_in[29], *ndb2 = (const float*)d_in[30];

  // ---- workspace layout (~162 MB) ----
  char* ws = (char*)d_ws;
  __hip_bfloat16* D1d  = (__hip_bfloat16*)(ws + 0);          // [64][512][512] = 33,554,432 B
  __hip_bfloat16* S    = (__hip_bfloat16*)(ws + 0);          // cell-major S aliases dead D1d
  __hip_bfloat16* D2dT = (__hip_bfloat16*)(ws + 33554432);   // 33,554,432 B
  __hip_bfloat16* S_fij = (__hip_bfloat16*)(ws + 67108864);  // 33,554,432 B
  float* row_part = (float*)(ws + 100663296);                // [32][512][128] = 8,388,608 B
  float* col_part = (float*)(ws + 117440512);                // [32][512][128]
  // ---- single zero-memset block [134,217,728 .. 140,910,608) ----
  float* Tc    = (float*)(ws + 134217728);                   // [16384][96] = 6,291,456 B
  int*   nC    = (int*)(ws + 140509184);                     // 1 int (+pad to 16)
  float* A     = (float*)(ws + 140509200);                   // 32768 floats
  float* B     = (float*)(ws + 140640272);                   // 32768 floats
  float* seg   = (float*)(ws + 140771344);                   // 1536 floats
  float* cnt   = (float*)(ws + 140777488);                   // 512 floats
  float* nb_t0 = (float*)(ws + 140779536);                   // 32768 floats -> end 140,910,608
  // ---- rest ----
  int*   slotmap  = (int*)(ws + 140910608);                  // 262144 ints (0xFF)
  int*   cells    = (int*)(ws + 143007760);                  // 16384 ints
  float* TWc      = (float*)(ws + 151461904);                // [16384][128]
  float* c1       = (float*)(ws + 159850512);                // 64
  float* c2       = (float*)(ws + 159850768);                // 64
  float* u        = (float*)(ws + 159851024);                // [512][128]
  float* v        = (float*)(ws + 160113168);                // [512][128]
  float* coord_diff  = (float*)(ws + 160375312);             // [512][3]
  float* efn         = (float*)(ws + 160381456);             // [512][64]
  float* diag_silu   = (float*)(ws + 160512528);             // [512][128]
  float* rowsum_silu = (float*)(ws + 160774672);
  float* colsum_silu = (float*)(ws + 161036816);
  float* diag_T      = (float*)(ws + 161298960);             // [512][64]
  float* row_T       = (float*)(ws + 161430032);
  float* col_T       = (float*)(ws + 161561104);
  float* tot         = (float*)(ws + 161692176);             // 64
  float* tr          = (float*)(ws + 161692432);             // 64
  float* nb_t1       = (float*)(ws + 161692688);             // [512][64]
  __hip_bfloat16* Wt  = (__hip_bfloat16*)(ws + 161823760);   // [128][64] -> 161,840,144

  float* out_h  = (float*)d_out;
  float* out_x  = out_h + 512 * 64;
  float* out_ea = out_x + 512 * 3;

  hipMemsetAsync(ws, 0, 67108864, stream);                   // D1d + D2dT zero
  hipMemsetAsync(slotmap, 0xFF, 1048576, stream);            // slotmap = -1
  hipMemsetAsync(ws + 134217728, 0, 6692880, stream);        // Tc..nb_t0

  k_edge<<<512, 128, 0, stream>>>(h, x, edges, ew1, eb1, ew2, eb2, coord_diff, efn);
  k_consts<<<1, 128, 0, stream>>>(p1b1, p1w2, p1b2, p2b1, p2w2, p2b2, c1, c2);
  k_prep<<<32, 256, 0, stream>>>(p3w1, Wt);
  k_mark<<<64, 256, 0, stream>>>(nb_edge, slotmap);
  k_compact<<<1024, 256, 0, stream>>>(slotmap, cells, nC);
  k_scatterT<<<8192, 192, 0, stream>>>(nb_edge, slotmap, coord_diff, efn, Tc);
  k_mlp96b<<<2048, 128, 0, stream>>>(cells, nC, Tc,
                                     p1w1, p1b1, p1w2, p1b2,
                                     p2w1, p2b1, p2w2, p2b2,
                                     c1, c2, p3w1, D1d, D2dT, A, B, TWc);
  k_uv<<<dim3(512, 2), 128, 0, stream>>>(A, B, c1, c2, p3w1, p3b1, u, v);
  k_einsum_mfma<<<1024, 256, 0, stream>>>(D1d, D2dT, S_fij);
  k_transpose<<<4096, 256, 0, stream>>>(S_fij, S);
  k_tout_mfma<<<1024, 256, 0, stream>>>(S, u, v, TWc, slotmap, Wt,
                                        row_part, col_part, diag_silu);
  k_sumparts<<<512, 256, 0, stream>>>(row_part, col_part, rowsum_silu, colsum_silu);
  k_tout2<<<dim3(512, 3), 64, 0, stream>>>(diag_silu, rowsum_silu, colsum_silu,
                                           p3w2, p3b2, diag_T, row_T, col_T);
  k_totr<<<1, 128, 0, stream>>>(row_T, diag_T, tot, tr);
  k_nbt1<<<512, 64, 0, stream>>>(diag_T, row_T, col_T, tot, tr, ignw, ignb, nb_t1);
  k_edge_out<<<512, 128, 0, stream>>>(edges, coord_diff, nb_t1, edge_attr,
                                      cw1, cb1, cw2, seg, cnt, nb_t0, out_ea);
  k_node_out<<<512, 128, 0, stream>>>(h, x, seg, cnt, nb_t0,
                                      ndw1, ndb1, ndw2, ndb2, out_h, out_x);
}